// Round 2
// baseline (431.106 us; speedup 1.0000x reference)
//
#include <hip/hip_runtime.h>
#include <stdint.h>

// N=4096, B=32, LATENT=16, UNITS=64, NNZ=65536, K=2, M=5.
#define NN    4096
#define BB    32
#define NNZE  65536
#define WA    512      // LATENT*B  (pass-A diffusion width, f32)
#define WB    2048     // UNITS*B   (pass-B diffusion width, bf16)

// ---------- bf16 helpers ----------
__device__ __forceinline__ float bf2f(unsigned int h) {
    union { unsigned int u; float f; } c; c.u = h << 16; return c.f;
}
__device__ __forceinline__ unsigned int f2bf(float f) {
    union { float ff; unsigned int u; } c; c.ff = f;
    return (c.u + 0x7fffu + ((c.u >> 16) & 1u)) >> 16;
}

// ---------- CSR build (both supports per launch) ----------
__global__ void hist2_kernel(const int* __restrict__ r1, const int* __restrict__ r2,
                             int* __restrict__ cnt1, int* __restrict__ cnt2) {
    int e = blockIdx.x * blockDim.x + threadIdx.x;   // < 2*NNZE
    if (e < NNZE) atomicAdd(&cnt1[r1[e]], 1);
    else          atomicAdd(&cnt2[r2[e - NNZE]], 1);
}

__global__ void scan2_kernel(int* cur1, int* rp1, int* cur2, int* rp2) {
    int* cur = (blockIdx.x == 0) ? cur1 : cur2;
    int* rp  = (blockIdx.x == 0) ? rp1  : rp2;
    __shared__ int part[256];
    int t = threadIdx.x;
    int base = t * 16;
    int loc[16];
    int s = 0;
#pragma unroll
    for (int i = 0; i < 16; ++i) { loc[i] = s; s += cur[base + i]; }
    part[t] = s;
    __syncthreads();
    for (int off = 1; off < 256; off <<= 1) {
        int v = 0;
        if (t >= off) v = part[t - off];
        __syncthreads();
        part[t] += v;
        __syncthreads();
    }
    int excl = (t == 0) ? 0 : part[t - 1];
#pragma unroll
    for (int i = 0; i < 16; ++i) rp[base + i] = excl + loc[i];
    __syncthreads();
#pragma unroll
    for (int i = 0; i < 16; ++i) cur[base + i] = rp[base + i];
    if (t == 255) rp[4096] = part[255];
}

// scatter (col,val) directly into CSR order — no perm indirection later
__global__ void scatter2_kernel(const int* __restrict__ r1, const int* __restrict__ c1, const float* __restrict__ v1,
                                const int* __restrict__ r2, const int* __restrict__ c2, const float* __restrict__ v2,
                                int* __restrict__ cur1, int* __restrict__ cur2,
                                int* __restrict__ ecol1, float* __restrict__ eval1,
                                int* __restrict__ ecol2, float* __restrict__ eval2) {
    int e = blockIdx.x * blockDim.x + threadIdx.x;
    if (e < NNZE) {
        int pos = atomicAdd(&cur1[r1[e]], 1);
        ecol1[pos] = c1[e]; eval1[pos] = v1[e];
    } else {
        int ee = e - NNZE;
        int pos = atomicAdd(&cur2[r2[ee]], 1);
        ecol2[pos] = c2[ee]; eval2[pos] = v2[ee];
    }
}

// ---------- transpose y -> x0 row layout [n][f*32+b] ----------
__global__ void transA_kernel(const float* __restrict__ y, float* __restrict__ x0) {
    __shared__ __align__(16) float srow[WA];
    int t = threadIdx.x, n = blockIdx.x;
    int b = t & 31, q = t >> 5;
    float4 y4 = *(const float4*)(y + (size_t)b * (NN * 16) + n * 16 + 4 * q);
    srow[(4 * q + 0) * 32 + b] = y4.x;
    srow[(4 * q + 1) * 32 + b] = y4.y;
    srow[(4 * q + 2) * 32 + b] = y4.z;
    srow[(4 * q + 3) * 32 + b] = y4.w;
    __syncthreads();
    ((float4*)(x0 + (size_t)n * WA))[t] = ((const float4*)srow)[t];
}

// ---------- pass-A spmm, both supports in one launch, pure gather ----------
// blockIdx < 4096 -> support1 row; else support2 row.
__global__ void spmmA2_kernel(const float* __restrict__ xin0, const float* __restrict__ xin1,
                              const float* __restrict__ xprev,
                              float* __restrict__ xout0, float* __restrict__ xout1,
                              const int* __restrict__ rp1, const int* __restrict__ ecol1, const float* __restrict__ eval1,
                              const int* __restrict__ rp2, const int* __restrict__ ecol2, const float* __restrict__ eval2,
                              float alpha, float beta) {
    __shared__ int scol[128];
    __shared__ float sval[128];
    int s = blockIdx.x >> 12;
    int row = blockIdx.x & 4095;
    const int*   rp   = s ? rp2   : rp1;
    const int*   ecol = s ? ecol2 : ecol1;
    const float* eval = s ? eval2 : eval1;
    const float* xin  = s ? xin1  : xin0;
    float*       xout = s ? xout1 : xout0;
    int t = threadIdx.x;   // 128 threads, float4 each
    int beg = rp[row], end = rp[row + 1];
    float4 acc = make_float4(0.f, 0.f, 0.f, 0.f);
    for (int i0 = beg; i0 < end; i0 += 128) {
        int nn = end - i0; if (nn > 128) nn = 128;
        __syncthreads();
        if (t < nn) { scol[t] = ecol[i0 + t]; sval[t] = eval[i0 + t]; }
        __syncthreads();
#pragma unroll 4
        for (int j = 0; j < nn; ++j) {
            float4 xv = ((const float4*)(xin + (size_t)scol[j] * WA))[t];
            float v = sval[j];
            acc.x += v * xv.x; acc.y += v * xv.y; acc.z += v * xv.z; acc.w += v * xv.w;
        }
    }
    float4 res;
    res.x = alpha * acc.x; res.y = alpha * acc.y; res.z = alpha * acc.z; res.w = alpha * acc.w;
    if (beta != 0.0f) {
        float4 pv = ((const float4*)(xprev + (size_t)row * WA))[t];
        res.x += beta * pv.x; res.y += beta * pv.y; res.z += beta * pv.z; res.w += beta * pv.w;
    }
    ((float4*)(xout + (size_t)row * WA))[t] = res;
}

// ---------- projA: 5 xA rows -> theta [n][32][16], tanh(hid)+bf16 -> xB0 ----------
__launch_bounds__(256)
__global__ void projA_kernel(const float* __restrict__ xA,   // [5][NN][WA] contiguous
                             const float* __restrict__ Wtheta, const float* __restrict__ Whid,
                             const float* __restrict__ b_hid,
                             float* __restrict__ theta,       // [NN][32][16]
                             unsigned short* __restrict__ xB0) {
    __shared__ __align__(16) float sX[5 * WA];      // 10 KB
    __shared__ __align__(16) float sWt[80 * 16];    //  5 KB
    __shared__ __align__(16) float sWh[80 * 64];    // 20 KB
    __shared__ __align__(16) float sB[WB];          //  8 KB (hid bounce, f32)
    int t = threadIdx.x, n = blockIdx.x;
    // weight panels, vectorized (layout identical: [(f*5+m)*16+u])
    for (int i = t; i < 320; i += 256) ((float4*)sWt)[i] = ((const float4*)Wtheta)[i];
    for (int i = t; i < 1280; i += 256) ((float4*)sWh)[i] = ((const float4*)Whid)[i];
    for (int i = t; i < 5 * 128; i += 256) {
        int m = i >> 7, k = i & 127;
        ((float4*)(sX + m * WA))[k] = ((const float4*)(xA + ((size_t)m * NN + n) * WA))[k];
    }
    __syncthreads();
    int b = t & 31, q = t >> 5;   // q in 0..7
    float tac0 = 0.f, tac1 = 0.f;
    float hac[8];
#pragma unroll
    for (int j = 0; j < 8; ++j) hac[j] = 0.f;
#pragma unroll 4
    for (int f = 0; f < 16; ++f) {
#pragma unroll
        for (int m = 0; m < 5; ++m) {
            float xf = sX[m * WA + f * 32 + b];
            int wr = f * 5 + m;
            float2 wt = *(const float2*)(sWt + wr * 16 + 2 * q);
            tac0 += xf * wt.x; tac1 += xf * wt.y;
            float4 wh0 = *(const float4*)(sWh + wr * 64 + 8 * q);
            float4 wh1 = *(const float4*)(sWh + wr * 64 + 8 * q + 4);
            hac[0] += xf * wh0.x; hac[1] += xf * wh0.y;
            hac[2] += xf * wh0.z; hac[3] += xf * wh0.w;
            hac[4] += xf * wh1.x; hac[5] += xf * wh1.y;
            hac[6] += xf * wh1.z; hac[7] += xf * wh1.w;
        }
    }
    *(float2*)(theta + ((size_t)n * 32 + b) * 16 + 2 * q) = make_float2(tac0, tac1);
#pragma unroll
    for (int j = 0; j < 8; ++j) sB[(8 * q + j) * 32 + b] = hac[j];
    __syncthreads();
    // coalesced bf16 write: thread t owns 8 consecutive elements
    int base = t * 8;
    float bh = b_hid[t >> 2];    // u = (t*8)>>5 constant across the 8
    float v[8];
#pragma unroll
    for (int j = 0; j < 8; ++j) v[j] = tanhf(sB[base + j] + bh);
    uint4 o;
    o.x = f2bf(v[0]) | (f2bf(v[1]) << 16);
    o.y = f2bf(v[2]) | (f2bf(v[3]) << 16);
    o.z = f2bf(v[4]) | (f2bf(v[5]) << 16);
    o.w = f2bf(v[6]) | (f2bf(v[7]) << 16);
    ((uint4*)(xB0 + (size_t)n * WB))[t] = o;
}

// ---------- pass-B spmm (bf16), both supports in one launch, pure gather ----------
__global__ void spmmB2_kernel(const unsigned short* __restrict__ xin0, const unsigned short* __restrict__ xin1,
                              const unsigned short* __restrict__ xprev,
                              unsigned short* __restrict__ xout0, unsigned short* __restrict__ xout1,
                              const int* __restrict__ rp1, const int* __restrict__ ecol1, const float* __restrict__ eval1,
                              const int* __restrict__ rp2, const int* __restrict__ ecol2, const float* __restrict__ eval2,
                              float alpha, float beta) {
    __shared__ int scol[256];
    __shared__ float sval[256];
    int s = blockIdx.x >> 12;
    int row = blockIdx.x & 4095;
    const int*   rp   = s ? rp2   : rp1;
    const int*   ecol = s ? ecol2 : ecol1;
    const float* eval = s ? eval2 : eval1;
    const unsigned short* xin = s ? xin1 : xin0;
    unsigned short*      xout = s ? xout1 : xout0;
    int t = threadIdx.x;   // 256 threads, 8 bf16 each (uint4)
    int beg = rp[row], end = rp[row + 1];
    float acc[8];
#pragma unroll
    for (int k = 0; k < 8; ++k) acc[k] = 0.f;
    for (int i0 = beg; i0 < end; i0 += 256) {
        int nn = end - i0; if (nn > 256) nn = 256;
        __syncthreads();
        if (t < nn) { scol[t] = ecol[i0 + t]; sval[t] = eval[i0 + t]; }
        __syncthreads();
#pragma unroll 4
        for (int j = 0; j < nn; ++j) {
            uint4 xv = ((const uint4*)(xin + (size_t)scol[j] * WB))[t];
            float v = sval[j];
            acc[0] += v * bf2f(xv.x & 0xffffu);
            acc[1] += v * bf2f(xv.x >> 16);
            acc[2] += v * bf2f(xv.y & 0xffffu);
            acc[3] += v * bf2f(xv.y >> 16);
            acc[4] += v * bf2f(xv.z & 0xffffu);
            acc[5] += v * bf2f(xv.z >> 16);
            acc[6] += v * bf2f(xv.w & 0xffffu);
            acc[7] += v * bf2f(xv.w >> 16);
        }
    }
    float r[8];
#pragma unroll
    for (int k = 0; k < 8; ++k) r[k] = alpha * acc[k];
    if (beta != 0.0f) {
        uint4 pv = ((const uint4*)(xprev + (size_t)row * WB))[t];
        r[0] += beta * bf2f(pv.x & 0xffffu);
        r[1] += beta * bf2f(pv.x >> 16);
        r[2] += beta * bf2f(pv.y & 0xffffu);
        r[3] += beta * bf2f(pv.y >> 16);
        r[4] += beta * bf2f(pv.z & 0xffffu);
        r[5] += beta * bf2f(pv.z >> 16);
        r[6] += beta * bf2f(pv.w & 0xffffu);
        r[7] += beta * bf2f(pv.w >> 16);
    }
    uint4 o;
    o.x = f2bf(r[0]) | (f2bf(r[1]) << 16);
    o.y = f2bf(r[2]) | (f2bf(r[3]) << 16);
    o.z = f2bf(r[4]) | (f2bf(r[5]) << 16);
    o.w = f2bf(r[6]) | (f2bf(r[7]) << 16);
    ((uint4*)(xout + (size_t)row * WB))[t] = o;
}

// ---------- projB: 5 xB rows + theta -> final output ----------
// 128 threads: b = t&31, hq = t>>5 (u-quad per thread, Ru=4).
__launch_bounds__(128)
__global__ void projB_kernel(const unsigned short* __restrict__ xB0, const unsigned short* __restrict__ xB1,
                             const unsigned short* __restrict__ xB2, const unsigned short* __restrict__ xB3,
                             const unsigned short* __restrict__ xB4,
                             const float* __restrict__ Wout, const float* __restrict__ b_lat,
                             const float* __restrict__ theta,   // [NN][32][16]
                             float* __restrict__ out) {         // [B][NN*16]
    __shared__ __align__(16) float sXB[5 * WB];     // 40 KB (f32-converted)
    __shared__ __align__(16) float sWo[320 * 16];   // 20 KB
    __shared__ __align__(16) float sOut[512];       //  2 KB bounce
    int t = threadIdx.x, n = blockIdx.x;
    // weight panel, vectorized (layout identical: [(up*5+m)*16+u])
    for (int i = t; i < 1280; i += 128) ((float4*)sWo)[i] = ((const float4*)Wout)[i];
#pragma unroll
    for (int m = 0; m < 5; ++m) {
        const unsigned short* xr;
        if (m == 0) xr = xB0; else if (m == 1) xr = xB1; else if (m == 2) xr = xB2;
        else if (m == 3) xr = xB3; else xr = xB4;
        const uint4* xr4 = (const uint4*)(xr + (size_t)n * WB);
#pragma unroll
        for (int k0 = 0; k0 < 2; ++k0) {
            int k = t + k0 * 128;
            uint4 xv = xr4[k];
            float4* d = (float4*)(sXB + m * WB + k * 8);
            d[0] = make_float4(bf2f(xv.x & 0xffffu), bf2f(xv.x >> 16),
                               bf2f(xv.y & 0xffffu), bf2f(xv.y >> 16));
            d[1] = make_float4(bf2f(xv.z & 0xffffu), bf2f(xv.z >> 16),
                               bf2f(xv.w & 0xffffu), bf2f(xv.w >> 16));
        }
    }
    __syncthreads();
    int b = t & 31, hq = t >> 5;   // hq in 0..3
    float a0 = 0.f, a1 = 0.f, a2 = 0.f, a3 = 0.f;
#pragma unroll 8
    for (int up = 0; up < 64; ++up) {
#pragma unroll
        for (int m = 0; m < 5; ++m) {
            float xf = sXB[m * WB + up * 32 + b];
            float4 w = *(const float4*)(sWo + (up * 5 + m) * 16 + 4 * hq);
            a0 += xf * w.x; a1 += xf * w.y; a2 += xf * w.z; a3 += xf * w.w;
        }
    }
    float4 th = *(const float4*)(theta + ((size_t)n * 32 + b) * 16 + 4 * hq);
    float4 bl = *(const float4*)(b_lat + 4 * hq);
    float4 res;
    res.x = -(1.f / (1.f + expf(-(th.x + bl.x)))) * tanhf(a0 + bl.x);
    res.y = -(1.f / (1.f + expf(-(th.y + bl.y)))) * tanhf(a1 + bl.y);
    res.z = -(1.f / (1.f + expf(-(th.z + bl.z)))) * tanhf(a2 + bl.z);
    res.w = -(1.f / (1.f + expf(-(th.w + bl.w)))) * tanhf(a3 + bl.w);
    *(float4*)(sOut + b * 16 + 4 * hq) = res;
    __syncthreads();
    // coalesced scatter: 4 consecutive lanes cover one 64B line per b
    int ob = t >> 2, oj = t & 3;
    float4 ov = *(const float4*)(sOut + ob * 16 + 4 * oj);
    *(float4*)(out + ((size_t)ob * NN + n) * 16 + 4 * oj) = ov;
}

extern "C" void kernel_launch(void* const* d_in, const int* in_sizes, int n_in,
                              void* d_out, int out_size, void* d_ws, size_t ws_size,
                              hipStream_t stream) {
    const float* y      = (const float*)d_in[1];
    const float* Wtheta = (const float*)d_in[2];
    const float* b_lat  = (const float*)d_in[3];
    const float* Whid   = (const float*)d_in[4];
    const float* b_hid  = (const float*)d_in[5];
    const float* Wout   = (const float*)d_in[6];
    const int*   r1     = (const int*)d_in[7];
    const int*   c1     = (const int*)d_in[8];
    const float* v1     = (const float*)d_in[9];
    const int*   r2     = (const int*)d_in[10];
    const int*   c2     = (const int*)d_in[11];
    const float* v2     = (const float*)d_in[12];
    float* out = (float*)d_out;

    // ---- workspace layout ----
    char* ws = (char*)d_ws;
    size_t off = 0;
    auto alloc = [&](size_t bytes) -> char* {
        char* p = ws + off;
        off += (bytes + 255) & ~(size_t)255;
        return p;
    };
    int*   rp1   = (int*)alloc(4097 * 4);
    int*   rp2   = (int*)alloc(4097 * 4);
    int*   cur1  = (int*)alloc(4096 * 4);            // cur1+cur2 contiguous (single memset)
    int*   cur2  = (int*)alloc(4096 * 4);
    int*   ecol1 = (int*)alloc(NNZE * 4);
    float* eval1 = (float*)alloc(NNZE * 4);
    int*   ecol2 = (int*)alloc(NNZE * 4);
    float* eval2 = (float*)alloc(NNZE * 4);
    float* theta = (float*)alloc((size_t)NN * 32 * 16 * 4);          //  8 MB
    float* xA    = (float*)alloc((size_t)5 * NN * WA * 4);           // 40 MB, [m][n][512]
    unsigned short* xB0 = (unsigned short*)alloc((size_t)NN * WB * 2); // 16 MB
    unsigned short* xB3 = (unsigned short*)alloc((size_t)NN * WB * 2); // 16 MB
    unsigned short* xB4 = (unsigned short*)alloc((size_t)NN * WB * 2); // 16 MB
    if (off > ws_size) return;   // fail loudly if ws too small
    // xA is dead after projA: overlay xB1/xB2 onto it (16 MB each, fits in 40 MB)
    float* xA0 = xA;
    float* xA1 = xA + (size_t)1 * NN * WA;
    float* xA2 = xA + (size_t)2 * NN * WA;
    float* xA3 = xA + (size_t)3 * NN * WA;
    float* xA4 = xA + (size_t)4 * NN * WA;
    unsigned short* xB1 = (unsigned short*)xA0;                      // bytes [0,16M) of xA block
    unsigned short* xB2 = (unsigned short*)xA2;                      // bytes [16M,32M)

    // ---- CSR build (edge arrays materialized in CSR order) ----
    hipMemsetAsync(cur1, 0, 2 * 4096 * 4, stream);
    hist2_kernel<<<2 * NNZE / 256, 256, 0, stream>>>(r1, r2, cur1, cur2);
    scan2_kernel<<<2, 256, 0, stream>>>(cur1, rp1, cur2, rp2);
    scatter2_kernel<<<2 * NNZE / 256, 256, 0, stream>>>(r1, c1, v1, r2, c2, v2,
                                                        cur1, cur2, ecol1, eval1, ecol2, eval2);

    // ---- pass A: transpose, 2 merged spmm launches, deferred projection ----
    transA_kernel<<<NN, 128, 0, stream>>>(y, xA0);
    spmmA2_kernel<<<2 * NN, 128, 0, stream>>>(xA0, xA0, xA0, xA1, xA3,
                                              rp1, ecol1, eval1, rp2, ecol2, eval2, 1.f, 0.f);
    spmmA2_kernel<<<2 * NN, 128, 0, stream>>>(xA1, xA3, xA0, xA2, xA4,
                                              rp1, ecol1, eval1, rp2, ecol2, eval2, 2.f, -1.f);
    projA_kernel<<<NN, 256, 0, stream>>>(xA, Wtheta, Whid, b_hid, theta, xB0);

    // ---- pass B: 2 merged spmm launches (bf16), deferred projection + epilogue ----
    spmmB2_kernel<<<2 * NN, 256, 0, stream>>>(xB0, xB0, xB0, xB1, xB3,
                                              rp1, ecol1, eval1, rp2, ecol2, eval2, 1.f, 0.f);
    spmmB2_kernel<<<2 * NN, 256, 0, stream>>>(xB1, xB3, xB0, xB2, xB4,
                                              rp1, ecol1, eval1, rp2, ecol2, eval2, 2.f, -1.f);
    projB_kernel<<<NN, 128, 0, stream>>>(xB0, xB1, xB2, xB3, xB4, Wout, b_lat, theta, out);
}

// Round 3
// 299.035 us; speedup vs baseline: 1.4417x; 1.4417x over previous
//
#include <hip/hip_runtime.h>
#include <stdint.h>

// N=4096, B=32, LATENT=16, UNITS=64, NNZ=65536, K=2, M=5.
#define NN    4096
#define BB    32
#define NNZE  65536
#define WA    512      // LATENT*B  (pass-A diffusion width, f32)
#define WB    2048     // UNITS*B   (c width, bf16)
#define WD    512      // pass-B post-projection diffusion width (16*B, bf16)

// ---------- bf16 helpers ----------
__device__ __forceinline__ float bf2f(unsigned int h) {
    union { unsigned int u; float f; } c; c.u = h << 16; return c.f;
}
__device__ __forceinline__ unsigned int f2bf(float f) {
    union { float ff; unsigned int u; } c; c.ff = f;
    return (c.u + 0x7fffu + ((c.u >> 16) & 1u)) >> 16;
}

// ---------- CSR build (both supports per launch) ----------
__global__ void hist2_kernel(const int* __restrict__ r1, const int* __restrict__ r2,
                             int* __restrict__ cnt1, int* __restrict__ cnt2) {
    int e = blockIdx.x * blockDim.x + threadIdx.x;   // < 2*NNZE
    if (e < NNZE) atomicAdd(&cnt1[r1[e]], 1);
    else          atomicAdd(&cnt2[r2[e - NNZE]], 1);
}

__global__ void scan2_kernel(int* cur1, int* rp1, int* cur2, int* rp2) {
    int* cur = (blockIdx.x == 0) ? cur1 : cur2;
    int* rp  = (blockIdx.x == 0) ? rp1  : rp2;
    __shared__ int part[256];
    int t = threadIdx.x;
    int base = t * 16;
    int loc[16];
    int s = 0;
#pragma unroll
    for (int i = 0; i < 16; ++i) { loc[i] = s; s += cur[base + i]; }
    part[t] = s;
    __syncthreads();
    for (int off = 1; off < 256; off <<= 1) {
        int v = 0;
        if (t >= off) v = part[t - off];
        __syncthreads();
        part[t] += v;
        __syncthreads();
    }
    int excl = (t == 0) ? 0 : part[t - 1];
#pragma unroll
    for (int i = 0; i < 16; ++i) rp[base + i] = excl + loc[i];
    __syncthreads();
#pragma unroll
    for (int i = 0; i < 16; ++i) cur[base + i] = rp[base + i];
    if (t == 255) rp[4096] = part[255];
}

// scatter (col,val) directly into CSR order
__global__ void scatter2_kernel(const int* __restrict__ r1, const int* __restrict__ c1, const float* __restrict__ v1,
                                const int* __restrict__ r2, const int* __restrict__ c2, const float* __restrict__ v2,
                                int* __restrict__ cur1, int* __restrict__ cur2,
                                int* __restrict__ ecol1, float* __restrict__ eval1,
                                int* __restrict__ ecol2, float* __restrict__ eval2) {
    int e = blockIdx.x * blockDim.x + threadIdx.x;
    if (e < NNZE) {
        int pos = atomicAdd(&cur1[r1[e]], 1);
        ecol1[pos] = c1[e]; eval1[pos] = v1[e];
    } else {
        int ee = e - NNZE;
        int pos = atomicAdd(&cur2[r2[ee]], 1);
        ecol2[pos] = c2[ee]; eval2[pos] = v2[ee];
    }
}

// ---------- transpose y -> x0 row layout [n][f*32+b] ----------
__global__ void transA_kernel(const float* __restrict__ y, float* __restrict__ x0) {
    __shared__ __align__(16) float srow[WA];
    int t = threadIdx.x, n = blockIdx.x;
    int b = t & 31, q = t >> 5;
    float4 y4 = *(const float4*)(y + (size_t)b * (NN * 16) + n * 16 + 4 * q);
    srow[(4 * q + 0) * 32 + b] = y4.x;
    srow[(4 * q + 1) * 32 + b] = y4.y;
    srow[(4 * q + 2) * 32 + b] = y4.z;
    srow[(4 * q + 3) * 32 + b] = y4.w;
    __syncthreads();
    ((float4*)(x0 + (size_t)n * WA))[t] = ((const float4*)srow)[t];
}

// ---------- pass-A spmm, both supports in one launch, pure gather ----------
__global__ void spmmA2_kernel(const float* __restrict__ xin0, const float* __restrict__ xin1,
                              const float* __restrict__ xprev,
                              float* __restrict__ xout0, float* __restrict__ xout1,
                              const int* __restrict__ rp1, const int* __restrict__ ecol1, const float* __restrict__ eval1,
                              const int* __restrict__ rp2, const int* __restrict__ ecol2, const float* __restrict__ eval2,
                              float alpha, float beta) {
    __shared__ int scol[128];
    __shared__ float sval[128];
    int s = blockIdx.x >> 12;
    int row = blockIdx.x & 4095;
    const int*   rp   = s ? rp2   : rp1;
    const int*   ecol = s ? ecol2 : ecol1;
    const float* eval = s ? eval2 : eval1;
    const float* xin  = s ? xin1  : xin0;
    float*       xout = s ? xout1 : xout0;
    int t = threadIdx.x;   // 128 threads, float4 each
    int beg = rp[row], end = rp[row + 1];
    float4 acc = make_float4(0.f, 0.f, 0.f, 0.f);
    for (int i0 = beg; i0 < end; i0 += 128) {
        int nn = end - i0; if (nn > 128) nn = 128;
        __syncthreads();
        if (t < nn) { scol[t] = ecol[i0 + t]; sval[t] = eval[i0 + t]; }
        __syncthreads();
#pragma unroll 4
        for (int j = 0; j < nn; ++j) {
            float4 xv = ((const float4*)(xin + (size_t)scol[j] * WA))[t];
            float v = sval[j];
            acc.x += v * xv.x; acc.y += v * xv.y; acc.z += v * xv.z; acc.w += v * xv.w;
        }
    }
    float4 res;
    res.x = alpha * acc.x; res.y = alpha * acc.y; res.z = alpha * acc.z; res.w = alpha * acc.w;
    if (beta != 0.0f) {
        float4 pv = ((const float4*)(xprev + (size_t)row * WA))[t];
        res.x += beta * pv.x; res.y += beta * pv.y; res.z += beta * pv.z; res.w += beta * pv.w;
    }
    ((float4*)(xout + (size_t)row * WA))[t] = res;
}

// ---------- projA: 5 xA rows -> theta [n][b][16], tanh(hid)+bf16 -> c ----------
__launch_bounds__(256)
__global__ void projA_kernel(const float* __restrict__ xA,   // [5][NN][WA] contiguous
                             const float* __restrict__ Wtheta, const float* __restrict__ Whid,
                             const float* __restrict__ b_hid,
                             float* __restrict__ theta,       // [NN][32][16]
                             unsigned short* __restrict__ c) {  // [NN][u*32+b] bf16
    __shared__ __align__(16) float sX[5 * WA];      // 10 KB
    __shared__ __align__(16) float sWt[80 * 16];    //  5 KB
    __shared__ __align__(16) float sWh[80 * 64];    // 20 KB
    __shared__ __align__(16) float sB[WB];          //  8 KB (hid bounce, f32)
    int t = threadIdx.x, n = blockIdx.x;
    for (int i = t; i < 320; i += 256) ((float4*)sWt)[i] = ((const float4*)Wtheta)[i];
    for (int i = t; i < 1280; i += 256) ((float4*)sWh)[i] = ((const float4*)Whid)[i];
    for (int i = t; i < 5 * 128; i += 256) {
        int m = i >> 7, k = i & 127;
        ((float4*)(sX + m * WA))[k] = ((const float4*)(xA + ((size_t)m * NN + n) * WA))[k];
    }
    __syncthreads();
    int b = t & 31, q = t >> 5;   // q in 0..7
    float tac0 = 0.f, tac1 = 0.f;
    float hac[8];
#pragma unroll
    for (int j = 0; j < 8; ++j) hac[j] = 0.f;
#pragma unroll 4
    for (int f = 0; f < 16; ++f) {
#pragma unroll
        for (int m = 0; m < 5; ++m) {
            float xf = sX[m * WA + f * 32 + b];
            int wr = f * 5 + m;
            float2 wt = *(const float2*)(sWt + wr * 16 + 2 * q);
            tac0 += xf * wt.x; tac1 += xf * wt.y;
            float4 wh0 = *(const float4*)(sWh + wr * 64 + 8 * q);
            float4 wh1 = *(const float4*)(sWh + wr * 64 + 8 * q + 4);
            hac[0] += xf * wh0.x; hac[1] += xf * wh0.y;
            hac[2] += xf * wh0.z; hac[3] += xf * wh0.w;
            hac[4] += xf * wh1.x; hac[5] += xf * wh1.y;
            hac[6] += xf * wh1.z; hac[7] += xf * wh1.w;
        }
    }
    *(float2*)(theta + ((size_t)n * 32 + b) * 16 + 2 * q) = make_float2(tac0, tac1);
#pragma unroll
    for (int j = 0; j < 8; ++j) sB[(8 * q + j) * 32 + b] = hac[j];
    __syncthreads();
    int base = t * 8;
    float bh = b_hid[t >> 2];    // u = (t*8)>>5 constant across the 8
    float v[8];
#pragma unroll
    for (int j = 0; j < 8; ++j) v[j] = tanhf(sB[base + j] + bh);
    uint4 o;
    o.x = f2bf(v[0]) | (f2bf(v[1]) << 16);
    o.y = f2bf(v[2]) | (f2bf(v[3]) << 16);
    o.z = f2bf(v[4]) | (f2bf(v[5]) << 16);
    o.w = f2bf(v[6]) | (f2bf(v[7]) << 16);
    ((uint4*)(c + (size_t)n * WB))[t] = o;
}

// ---------- preproj: d_m = c @ Wout_m  (project BEFORE diffusion) ----------
// d layout per row: [b*16+u']. d0 f32 (final-only), d1..d4 bf16 (spmm inputs).
// Block: 256 threads = 2 groups x (b,uq); each thread handles R=2 rows. 4 n/block.
__launch_bounds__(256)
__global__ void preproj_kernel(const unsigned short* __restrict__ c,   // [NN][u*32+b] bf16
                               const float* __restrict__ Wout,         // [(u*5+m)*16+u']
                               float* __restrict__ d0,
                               unsigned short* __restrict__ dd1, unsigned short* __restrict__ dd2,
                               unsigned short* __restrict__ dd3, unsigned short* __restrict__ dd4) {
    __shared__ __align__(16) float sWo[320 * 16];          // 20 KB
    __shared__ __align__(16) unsigned short sC[4 * WB];    // 16 KB
    int t = threadIdx.x;
    int n0 = blockIdx.x * 4;
    for (int i = t; i < 1280; i += 256) ((float4*)sWo)[i] = ((const float4*)Wout)[i];
    for (int i = t; i < 1024; i += 256) {
        int r = i >> 8, k = i & 255;
        ((uint4*)(sC + r * WB))[k] = ((const uint4*)(c + (size_t)(n0 + r) * WB))[k];
    }
    __syncthreads();
    int uq = t & 3, b = (t >> 2) & 31, g = t >> 7;   // g: row-pair group
    float acc[2][5][4];
#pragma unroll
    for (int r = 0; r < 2; ++r)
#pragma unroll
        for (int m = 0; m < 5; ++m)
#pragma unroll
            for (int j = 0; j < 4; ++j) acc[r][m][j] = 0.f;
#pragma unroll 2
    for (int u = 0; u < 64; ++u) {
        float c0 = bf2f(sC[(g * 2 + 0) * WB + u * 32 + b]);
        float c1 = bf2f(sC[(g * 2 + 1) * WB + u * 32 + b]);
#pragma unroll
        for (int m = 0; m < 5; ++m) {
            float4 w = *(const float4*)(sWo + (u * 5 + m) * 16 + 4 * uq);
            acc[0][m][0] += c0 * w.x; acc[0][m][1] += c0 * w.y;
            acc[0][m][2] += c0 * w.z; acc[0][m][3] += c0 * w.w;
            acc[1][m][0] += c1 * w.x; acc[1][m][1] += c1 * w.y;
            acc[1][m][2] += c1 * w.z; acc[1][m][3] += c1 * w.w;
        }
    }
#pragma unroll
    for (int r = 0; r < 2; ++r) {
        int n = n0 + g * 2 + r;
        size_t base = (size_t)n * WD + b * 16 + 4 * uq;
        *(float4*)(d0 + base) = make_float4(acc[r][0][0], acc[r][0][1], acc[r][0][2], acc[r][0][3]);
        uint2 o1, o2, o3, o4;
        o1.x = f2bf(acc[r][1][0]) | (f2bf(acc[r][1][1]) << 16);
        o1.y = f2bf(acc[r][1][2]) | (f2bf(acc[r][1][3]) << 16);
        o2.x = f2bf(acc[r][2][0]) | (f2bf(acc[r][2][1]) << 16);
        o2.y = f2bf(acc[r][2][2]) | (f2bf(acc[r][2][3]) << 16);
        o3.x = f2bf(acc[r][3][0]) | (f2bf(acc[r][3][1]) << 16);
        o3.y = f2bf(acc[r][3][2]) | (f2bf(acc[r][3][3]) << 16);
        o4.x = f2bf(acc[r][4][0]) | (f2bf(acc[r][4][1]) << 16);
        o4.y = f2bf(acc[r][4][2]) | (f2bf(acc[r][4][3]) << 16);
        *(uint2*)(dd1 + base) = o1;
        *(uint2*)(dd2 + base) = o2;
        *(uint2*)(dd3 + base) = o3;
        *(uint2*)(dd4 + base) = o4;
    }
}

// ---------- spmmD: 512-wide bf16 spmm, multi-instance, XCD-swizzled ----------
struct SpmmDesc {
    const unsigned short* in;     // [NN][512] bf16
    const unsigned short* prev;   // nullptr if beta==0
    float* outF;                  // exactly one of outF/outH non-null
    unsigned short* outH;
    const int* rp; const int* ecol; const float* eval;
    float alpha, beta;
};

__launch_bounds__(64)
__global__ void spmmD_kernel(SpmmDesc q0, SpmmDesc q1, SpmmDesc q2, SpmmDesc q3, int ninst) {
    __shared__ int scol[64];
    __shared__ float sval[64];
    int blk = blockIdx.x;
    int xcd = blk & 7;
    int idx = blk >> 3;
    int spx = 8 / ninst;                 // XCD slots per instance
    int inst = xcd / spx;                // keep each instance's gathers on few XCDs (L2 locality)
    int sub  = xcd - inst * spx;
    int row  = sub * (NN / spx) + idx;   // bijective over (inst,row)
    SpmmDesc q = (inst == 0) ? q0 : (inst == 1) ? q1 : (inst == 2) ? q2 : q3;
    int t = threadIdx.x;   // 64 threads, uint4 (8 bf16) each
    int beg = q.rp[row], end = q.rp[row + 1];
    float acc[8];
#pragma unroll
    for (int k = 0; k < 8; ++k) acc[k] = 0.f;
    for (int i0 = beg; i0 < end; i0 += 64) {
        int nn = end - i0; if (nn > 64) nn = 64;
        __syncthreads();
        if (t < nn) { scol[t] = q.ecol[i0 + t]; sval[t] = q.eval[i0 + t]; }
        __syncthreads();
#pragma unroll 4
        for (int j = 0; j < nn; ++j) {
            uint4 xv = ((const uint4*)(q.in + (size_t)scol[j] * WD))[t];
            float v = sval[j];
            acc[0] += v * bf2f(xv.x & 0xffffu);
            acc[1] += v * bf2f(xv.x >> 16);
            acc[2] += v * bf2f(xv.y & 0xffffu);
            acc[3] += v * bf2f(xv.y >> 16);
            acc[4] += v * bf2f(xv.z & 0xffffu);
            acc[5] += v * bf2f(xv.z >> 16);
            acc[6] += v * bf2f(xv.w & 0xffffu);
            acc[7] += v * bf2f(xv.w >> 16);
        }
    }
    float r[8];
#pragma unroll
    for (int k = 0; k < 8; ++k) r[k] = q.alpha * acc[k];
    if (q.prev) {
        uint4 pv = ((const uint4*)(q.prev + (size_t)row * WD))[t];
        r[0] += q.beta * bf2f(pv.x & 0xffffu);
        r[1] += q.beta * bf2f(pv.x >> 16);
        r[2] += q.beta * bf2f(pv.y & 0xffffu);
        r[3] += q.beta * bf2f(pv.y >> 16);
        r[4] += q.beta * bf2f(pv.z & 0xffffu);
        r[5] += q.beta * bf2f(pv.z >> 16);
        r[6] += q.beta * bf2f(pv.w & 0xffffu);
        r[7] += q.beta * bf2f(pv.w >> 16);
    }
    if (q.outF) {
        float* po = q.outF + (size_t)row * WD + t * 8;
        *(float4*)(po)     = make_float4(r[0], r[1], r[2], r[3]);
        *(float4*)(po + 4) = make_float4(r[4], r[5], r[6], r[7]);
    } else {
        uint4 o;
        o.x = f2bf(r[0]) | (f2bf(r[1]) << 16);
        o.y = f2bf(r[2]) | (f2bf(r[3]) << 16);
        o.z = f2bf(r[4]) | (f2bf(r[5]) << 16);
        o.w = f2bf(r[6]) | (f2bf(r[7]) << 16);
        ((uint4*)(q.outH + (size_t)row * WD))[t] = o;
    }
}

// ---------- final: out = -sigmoid(theta+bl) * tanh(d0+w1+z2+w3+z4+bl) ----------
__global__ void final2_kernel(const float* __restrict__ theta, const float* __restrict__ d0,
                              const float* __restrict__ w1, const float* __restrict__ z2,
                              const float* __restrict__ w3, const float* __restrict__ z4,
                              const float* __restrict__ b_lat, float* __restrict__ out) {
    int i4 = blockIdx.x * blockDim.x + threadIdx.x;   // float4 index < NN*512/4
    size_t i = (size_t)i4 * 4;
    int u = (int)(i & 15);
    int b = (int)((i >> 4) & 31);
    int n = (int)(i >> 9);
    float4 tv = *(const float4*)(theta + i);
    float4 a0 = *(const float4*)(d0 + i);
    float4 a1 = *(const float4*)(w1 + i);
    float4 a2 = *(const float4*)(z2 + i);
    float4 a3 = *(const float4*)(w3 + i);
    float4 a4 = *(const float4*)(z4 + i);
    float4 bl = *(const float4*)(b_lat + u);
    float sx = a0.x + a1.x + a2.x + a3.x + a4.x + bl.x;
    float sy = a0.y + a1.y + a2.y + a3.y + a4.y + bl.y;
    float sz = a0.z + a1.z + a2.z + a3.z + a4.z + bl.z;
    float sw = a0.w + a1.w + a2.w + a3.w + a4.w + bl.w;
    float4 res;
    res.x = -(1.f / (1.f + expf(-(tv.x + bl.x)))) * tanhf(sx);
    res.y = -(1.f / (1.f + expf(-(tv.y + bl.y)))) * tanhf(sy);
    res.z = -(1.f / (1.f + expf(-(tv.z + bl.z)))) * tanhf(sz);
    res.w = -(1.f / (1.f + expf(-(tv.w + bl.w)))) * tanhf(sw);
    *(float4*)(out + ((size_t)b * NN + n) * 16 + u) = res;
}

extern "C" void kernel_launch(void* const* d_in, const int* in_sizes, int n_in,
                              void* d_out, int out_size, void* d_ws, size_t ws_size,
                              hipStream_t stream) {
    const float* y      = (const float*)d_in[1];
    const float* Wtheta = (const float*)d_in[2];
    const float* b_lat  = (const float*)d_in[3];
    const float* Whid   = (const float*)d_in[4];
    const float* b_hid  = (const float*)d_in[5];
    const float* Wout   = (const float*)d_in[6];
    const int*   r1     = (const int*)d_in[7];
    const int*   c1     = (const int*)d_in[8];
    const float* v1     = (const float*)d_in[9];
    const int*   r2     = (const int*)d_in[10];
    const int*   c2     = (const int*)d_in[11];
    const float* v2     = (const float*)d_in[12];
    float* out = (float*)d_out;

    // ---- workspace layout ----
    char* ws = (char*)d_ws;
    size_t off = 0;
    auto alloc = [&](size_t bytes) -> char* {
        char* p = ws + off;
        off += (bytes + 255) & ~(size_t)255;
        return p;
    };
    int*   rp1   = (int*)alloc(4097 * 4);
    int*   rp2   = (int*)alloc(4097 * 4);
    int*   cur1  = (int*)alloc(4096 * 4);            // cur1+cur2 contiguous (single memset)
    int*   cur2  = (int*)alloc(4096 * 4);
    int*   ecol1 = (int*)alloc(NNZE * 4);
    float* eval1 = (float*)alloc(NNZE * 4);
    int*   ecol2 = (int*)alloc(NNZE * 4);
    float* eval2 = (float*)alloc(NNZE * 4);
    float* theta = (float*)alloc((size_t)NN * 32 * 16 * 4);            //  8 MB
    char*  xAreg = alloc((size_t)5 * NN * WA * 4);                     // 40 MB
    char*  xBreg = alloc((size_t)NN * WB * 2);                         // 16 MB (c bf16)
    unsigned short* w2h = (unsigned short*)alloc((size_t)NN * WD * 2); //  4 MB
    unsigned short* w4h = (unsigned short*)alloc((size_t)NN * WD * 2); //  4 MB
    float* z2 = (float*)alloc((size_t)NN * WD * 4);                    //  8 MB
    float* z4 = (float*)alloc((size_t)NN * WD * 4);                    //  8 MB
    if (off > ws_size) return;   // fail loudly if ws too small

    float* xA  = (float*)xAreg;                  // [5][NN][WA]
    float* xA0 = xA;
    float* xA1 = xA + (size_t)1 * NN * WA;
    float* xA2 = xA + (size_t)2 * NN * WA;
    float* xA3 = xA + (size_t)3 * NN * WA;
    float* xA4 = xA + (size_t)4 * NN * WA;
    unsigned short* cbuf = (unsigned short*)xBreg;
    // xA dead after projA -> overlay d buffers (24 MB of 40)
    float*          d0  = (float*)xAreg;                                  // 8 MB f32
    unsigned short* dd1 = (unsigned short*)(xAreg + ((size_t)8  << 20));  // 4 MB bf16
    unsigned short* dd2 = (unsigned short*)(xAreg + ((size_t)12 << 20));
    unsigned short* dd3 = (unsigned short*)(xAreg + ((size_t)16 << 20));
    unsigned short* dd4 = (unsigned short*)(xAreg + ((size_t)20 << 20));
    // c dead after preproj -> overlay w1/w3 (f32, final-only)
    float* w1 = (float*)xBreg;
    float* w3 = (float*)(xBreg + ((size_t)8 << 20));

    // ---- CSR build ----
    hipMemsetAsync(cur1, 0, 2 * 4096 * 4, stream);
    hist2_kernel<<<2 * NNZE / 256, 256, 0, stream>>>(r1, r2, cur1, cur2);
    scan2_kernel<<<2, 256, 0, stream>>>(cur1, rp1, cur2, rp2);
    scatter2_kernel<<<2 * NNZE / 256, 256, 0, stream>>>(r1, c1, v1, r2, c2, v2,
                                                        cur1, cur2, ecol1, eval1, ecol2, eval2);

    // ---- pass A: transpose, 2 merged spmm launches, projection ----
    transA_kernel<<<NN, 128, 0, stream>>>(y, xA0);
    spmmA2_kernel<<<2 * NN, 128, 0, stream>>>(xA0, xA0, xA0, xA1, xA3,
                                              rp1, ecol1, eval1, rp2, ecol2, eval2, 1.f, 0.f);
    spmmA2_kernel<<<2 * NN, 128, 0, stream>>>(xA1, xA3, xA0, xA2, xA4,
                                              rp1, ecol1, eval1, rp2, ecol2, eval2, 2.f, -1.f);
    projA_kernel<<<NN, 256, 0, stream>>>(xA, Wtheta, Whid, b_hid, theta, cbuf);

    // ---- pass B (commuted): pre-project, then narrow (512-wide) diffusions ----
    preproj_kernel<<<NN / 4, 256, 0, stream>>>(cbuf, Wout, d0, dd1, dd2, dd3, dd4);
    // launch1: w1=S1@d1 (f32), w2=S1@d2 (bf16), w3=S2@d3 (f32), w4=S2@d4 (bf16)
    SpmmDesc a0 = { dd1, nullptr, w1, nullptr, rp1, ecol1, eval1, 1.f, 0.f };
    SpmmDesc a1 = { dd2, nullptr, nullptr, w2h, rp1, ecol1, eval1, 1.f, 0.f };
    SpmmDesc a2 = { dd3, nullptr, w3, nullptr, rp2, ecol2, eval2, 1.f, 0.f };
    SpmmDesc a3 = { dd4, nullptr, nullptr, w4h, rp2, ecol2, eval2, 1.f, 0.f };
    spmmD_kernel<<<4 * NN, 64, 0, stream>>>(a0, a1, a2, a3, 4);
    // launch2: z2 = 2*S1@w2 - d2 (f32), z4 = 2*S2@w4 - d4 (f32)
    SpmmDesc b0 = { w2h, dd2, z2, nullptr, rp1, ecol1, eval1, 2.f, -1.f };
    SpmmDesc b1 = { w4h, dd4, z4, nullptr, rp2, ecol2, eval2, 2.f, -1.f };
    spmmD_kernel<<<2 * NN, 64, 0, stream>>>(b0, b1, b0, b1, 2);

    // ---- epilogue ----
    final2_kernel<<<(NN * WD) / 4 / 256, 256, 0, stream>>>(theta, d0, w1, z2, w3, z4, b_lat, out);
}

// Round 4
// 261.577 us; speedup vs baseline: 1.6481x; 1.1432x over previous
//
#include <hip/hip_runtime.h>
#include <stdint.h>

// N=4096, B=32, LATENT=16, UNITS=64, NNZ=65536, K=2, M=5.
#define NN    4096
#define BB    32
#define NNZE  65536
#define WA    512      // LATENT*B  (pass-A diffusion width)
#define WB    2048     // UNITS*B   (c width, bf16)
#define WD    512      // narrow diffusion width (16*B)

// ---------- bf16 helpers ----------
__device__ __forceinline__ float bf2f(unsigned int h) {
    union { unsigned int u; float f; } c; c.u = h << 16; return c.f;
}
__device__ __forceinline__ unsigned int f2bf(float f) {
    union { float ff; unsigned int u; } c; c.ff = f;
    return (c.u + 0x7fffu + ((c.u >> 16) & 1u)) >> 16;
}

// ---------- CSR build (both supports per launch) ----------
__global__ void hist2_kernel(const int* __restrict__ r1, const int* __restrict__ r2,
                             int* __restrict__ cnt1, int* __restrict__ cnt2) {
    int e = blockIdx.x * blockDim.x + threadIdx.x;   // < 2*NNZE
    if (e < NNZE) atomicAdd(&cnt1[r1[e]], 1);
    else          atomicAdd(&cnt2[r2[e - NNZE]], 1);
}

__global__ void scan2_kernel(int* cur1, int* rp1, int* cur2, int* rp2) {
    int* cur = (blockIdx.x == 0) ? cur1 : cur2;
    int* rp  = (blockIdx.x == 0) ? rp1  : rp2;
    __shared__ int part[256];
    int t = threadIdx.x;
    int base = t * 16;
    int loc[16];
    int s = 0;
#pragma unroll
    for (int i = 0; i < 16; ++i) { loc[i] = s; s += cur[base + i]; }
    part[t] = s;
    __syncthreads();
    for (int off = 1; off < 256; off <<= 1) {
        int v = 0;
        if (t >= off) v = part[t - off];
        __syncthreads();
        part[t] += v;
        __syncthreads();
    }
    int excl = (t == 0) ? 0 : part[t - 1];
#pragma unroll
    for (int i = 0; i < 16; ++i) rp[base + i] = excl + loc[i];
    __syncthreads();
#pragma unroll
    for (int i = 0; i < 16; ++i) cur[base + i] = rp[base + i];
    if (t == 255) rp[4096] = part[255];
}

// scatter (col,val) directly into CSR order
__global__ void scatter2_kernel(const int* __restrict__ r1, const int* __restrict__ c1, const float* __restrict__ v1,
                                const int* __restrict__ r2, const int* __restrict__ c2, const float* __restrict__ v2,
                                int* __restrict__ cur1, int* __restrict__ cur2,
                                int* __restrict__ ecol1, float* __restrict__ eval1,
                                int* __restrict__ ecol2, float* __restrict__ eval2) {
    int e = blockIdx.x * blockDim.x + threadIdx.x;
    if (e < NNZE) {
        int pos = atomicAdd(&cur1[r1[e]], 1);
        ecol1[pos] = c1[e]; eval1[pos] = v1[e];
    } else {
        int ee = e - NNZE;
        int pos = atomicAdd(&cur2[r2[ee]], 1);
        ecol2[pos] = c2[ee]; eval2[pos] = v2[ee];
    }
}

// ---------- transpose y -> x0 row layout [n][f*32+b], bf16 ----------
__global__ void transA_kernel(const float* __restrict__ y, unsigned short* __restrict__ x0h) {
    __shared__ __align__(16) unsigned short srow[WA];
    int t = threadIdx.x, n = blockIdx.x;
    int b = t & 31, q = t >> 5;
    float4 y4 = *(const float4*)(y + (size_t)b * (NN * 16) + n * 16 + 4 * q);
    srow[(4 * q + 0) * 32 + b] = (unsigned short)f2bf(y4.x);
    srow[(4 * q + 1) * 32 + b] = (unsigned short)f2bf(y4.y);
    srow[(4 * q + 2) * 32 + b] = (unsigned short)f2bf(y4.z);
    srow[(4 * q + 3) * 32 + b] = (unsigned short)f2bf(y4.w);
    __syncthreads();
    ((uint2*)(x0h + (size_t)n * WA))[t] = ((const uint2*)srow)[t];
}

// ---------- spmmD: 512-wide bf16 spmm, multi-instance, XCD-chunked ----------
struct SpmmDesc {
    const unsigned short* in;     // [NN][512] bf16
    const unsigned short* prev;   // nullptr if beta==0
    float* outF;                  // exactly one of outF/outH non-null
    unsigned short* outH;
    const int* rp; const int* ecol; const float* eval;
    float alpha, beta;
};

__launch_bounds__(64)
__global__ void spmmD_kernel(SpmmDesc q0, SpmmDesc q1, SpmmDesc q2, SpmmDesc q3, int ninst) {
    __shared__ int scol[64];
    __shared__ float sval[64];
    int blk = blockIdx.x;
    int xcd = blk & 7;
    int idx = blk >> 3;
    int spx = 8 / ninst;                 // XCD slots per instance
    int inst = xcd / spx;                // each instance's 4MB source stays L2-resident per XCD
    int sub  = xcd - inst * spx;
    int row  = sub * (NN / spx) + idx;   // bijective over (inst,row)
    SpmmDesc q = (inst == 0) ? q0 : (inst == 1) ? q1 : (inst == 2) ? q2 : q3;
    int t = threadIdx.x;   // 64 threads, uint4 (8 bf16) each
    int beg = q.rp[row], end = q.rp[row + 1];
    float acc[8];
#pragma unroll
    for (int k = 0; k < 8; ++k) acc[k] = 0.f;
    for (int i0 = beg; i0 < end; i0 += 64) {
        int nn = end - i0; if (nn > 64) nn = 64;
        __syncthreads();
        if (t < nn) { scol[t] = q.ecol[i0 + t]; sval[t] = q.eval[i0 + t]; }
        __syncthreads();
#pragma unroll 4
        for (int j = 0; j < nn; ++j) {
            uint4 xv = ((const uint4*)(q.in + (size_t)scol[j] * WD))[t];
            float v = sval[j];
            acc[0] += v * bf2f(xv.x & 0xffffu);
            acc[1] += v * bf2f(xv.x >> 16);
            acc[2] += v * bf2f(xv.y & 0xffffu);
            acc[3] += v * bf2f(xv.y >> 16);
            acc[4] += v * bf2f(xv.z & 0xffffu);
            acc[5] += v * bf2f(xv.z >> 16);
            acc[6] += v * bf2f(xv.w & 0xffffu);
            acc[7] += v * bf2f(xv.w >> 16);
        }
    }
    float r[8];
#pragma unroll
    for (int k = 0; k < 8; ++k) r[k] = q.alpha * acc[k];
    if (q.prev) {
        uint4 pv = ((const uint4*)(q.prev + (size_t)row * WD))[t];
        r[0] += q.beta * bf2f(pv.x & 0xffffu);
        r[1] += q.beta * bf2f(pv.x >> 16);
        r[2] += q.beta * bf2f(pv.y & 0xffffu);
        r[3] += q.beta * bf2f(pv.y >> 16);
        r[4] += q.beta * bf2f(pv.z & 0xffffu);
        r[5] += q.beta * bf2f(pv.z >> 16);
        r[6] += q.beta * bf2f(pv.w & 0xffffu);
        r[7] += q.beta * bf2f(pv.w >> 16);
    }
    if (q.outF) {
        float* po = q.outF + (size_t)row * WD + t * 8;
        *(float4*)(po)     = make_float4(r[0], r[1], r[2], r[3]);
        *(float4*)(po + 4) = make_float4(r[4], r[5], r[6], r[7]);
    } else {
        uint4 o;
        o.x = f2bf(r[0]) | (f2bf(r[1]) << 16);
        o.y = f2bf(r[2]) | (f2bf(r[3]) << 16);
        o.z = f2bf(r[4]) | (f2bf(r[5]) << 16);
        o.w = f2bf(r[6]) | (f2bf(r[7]) << 16);
        ((uint4*)(q.outH + (size_t)row * WD))[t] = o;
    }
}

// ---------- projA: 5 bf16 x-rows (2 n per block) -> theta, tanh(hid) -> c ----------
__launch_bounds__(256)
__global__ void projA_kernel(const unsigned short* __restrict__ xh,   // [5][NN][512] bf16
                             const float* __restrict__ Wtheta, const float* __restrict__ Whid,
                             const float* __restrict__ b_hid,
                             float* __restrict__ theta,       // [NN][32][16]
                             unsigned short* __restrict__ c) {  // [NN][u*32+b] bf16
    __shared__ __align__(16) float sWt[80 * 16];    //  5 KB
    __shared__ __align__(16) float sWh[80 * 64];    // 20 KB
    __shared__ __align__(16) float sX[10 * 512];    // 20 KB  [(r*5+m)*512 + f*32+b]
    __shared__ __align__(16) float sB[64 * 33];     // 8.25 KB (padded bounce: u*33+b)
    int t = threadIdx.x;
    int n0 = blockIdx.x * 2;
    for (int i = t; i < 320; i += 256) ((float4*)sWt)[i] = ((const float4*)Wtheta)[i];
    for (int i = t; i < 1280; i += 256) ((float4*)sWh)[i] = ((const float4*)Whid)[i];
    for (int i = t; i < 640; i += 256) {
        int chunk = i >> 6, k = i & 63;
        int m = chunk % 5, r = chunk / 5;
        uint4 xv = ((const uint4*)(xh + ((size_t)m * NN + n0 + r) * WA))[k];
        float* d = sX + (r * 5 + m) * 512 + k * 8;
        d[0] = bf2f(xv.x & 0xffffu); d[1] = bf2f(xv.x >> 16);
        d[2] = bf2f(xv.y & 0xffffu); d[3] = bf2f(xv.y >> 16);
        d[4] = bf2f(xv.z & 0xffffu); d[5] = bf2f(xv.z >> 16);
        d[6] = bf2f(xv.w & 0xffffu); d[7] = bf2f(xv.w >> 16);
    }
    __syncthreads();
    int b = t & 31, q = t >> 5;   // q in 0..7
    float tac[2][2];
    float hac[2][8];
#pragma unroll
    for (int r = 0; r < 2; ++r) {
        tac[r][0] = 0.f; tac[r][1] = 0.f;
#pragma unroll
        for (int j = 0; j < 8; ++j) hac[r][j] = 0.f;
    }
#pragma unroll 4
    for (int f = 0; f < 16; ++f) {
#pragma unroll
        for (int m = 0; m < 5; ++m) {
            int wr = f * 5 + m;
            float xf0 = sX[(0 + m) * 512 + f * 32 + b];
            float xf1 = sX[(5 + m) * 512 + f * 32 + b];
            float2 wt = *(const float2*)(sWt + wr * 16 + 2 * q);
            float4 wh0 = *(const float4*)(sWh + wr * 64 + 8 * q);
            float4 wh1 = *(const float4*)(sWh + wr * 64 + 8 * q + 4);
            tac[0][0] += xf0 * wt.x; tac[0][1] += xf0 * wt.y;
            tac[1][0] += xf1 * wt.x; tac[1][1] += xf1 * wt.y;
            hac[0][0] += xf0 * wh0.x; hac[0][1] += xf0 * wh0.y;
            hac[0][2] += xf0 * wh0.z; hac[0][3] += xf0 * wh0.w;
            hac[0][4] += xf0 * wh1.x; hac[0][5] += xf0 * wh1.y;
            hac[0][6] += xf0 * wh1.z; hac[0][7] += xf0 * wh1.w;
            hac[1][0] += xf1 * wh0.x; hac[1][1] += xf1 * wh0.y;
            hac[1][2] += xf1 * wh0.z; hac[1][3] += xf1 * wh0.w;
            hac[1][4] += xf1 * wh1.x; hac[1][5] += xf1 * wh1.y;
            hac[1][6] += xf1 * wh1.z; hac[1][7] += xf1 * wh1.w;
        }
    }
#pragma unroll
    for (int r = 0; r < 2; ++r)
        *(float2*)(theta + ((size_t)(n0 + r) * 32 + b) * 16 + 2 * q) = make_float2(tac[r][0], tac[r][1]);
    float bh = b_hid[t >> 2];    // u = (t*8)>>5 constant across the thread's 8 elems
#pragma unroll
    for (int r = 0; r < 2; ++r) {
        __syncthreads();
#pragma unroll
        for (int j = 0; j < 8; ++j) sB[(8 * q + j) * 33 + b] = hac[r][j];
        __syncthreads();
        int rb = (t >> 2) * 33 + (t & 3) * 8;   // padded read base (conflict-free)
        float v[8];
#pragma unroll
        for (int j = 0; j < 8; ++j) v[j] = tanhf(sB[rb + j] + bh);
        uint4 o;
        o.x = f2bf(v[0]) | (f2bf(v[1]) << 16);
        o.y = f2bf(v[2]) | (f2bf(v[3]) << 16);
        o.z = f2bf(v[4]) | (f2bf(v[5]) << 16);
        o.w = f2bf(v[6]) | (f2bf(v[7]) << 16);
        ((uint4*)(c + (size_t)(n0 + r) * WB))[t] = o;
    }
}

// ---------- preproj: d_m = c @ Wout_m  (project BEFORE diffusion) ----------
__launch_bounds__(256)
__global__ void preproj_kernel(const unsigned short* __restrict__ c,   // [NN][u*32+b] bf16
                               const float* __restrict__ Wout,         // [(u*5+m)*16+u']
                               float* __restrict__ d0,
                               unsigned short* __restrict__ dd1, unsigned short* __restrict__ dd2,
                               unsigned short* __restrict__ dd3, unsigned short* __restrict__ dd4) {
    __shared__ __align__(16) float sWo[320 * 16];          // 20 KB
    __shared__ __align__(16) unsigned short sC[4 * WB];    // 16 KB
    int t = threadIdx.x;
    int n0 = blockIdx.x * 4;
    for (int i = t; i < 1280; i += 256) ((float4*)sWo)[i] = ((const float4*)Wout)[i];
    for (int i = t; i < 1024; i += 256) {
        int r = i >> 8, k = i & 255;
        ((uint4*)(sC + r * WB))[k] = ((const uint4*)(c + (size_t)(n0 + r) * WB))[k];
    }
    __syncthreads();
    int uq = t & 3, b = (t >> 2) & 31, g = t >> 7;   // g: row-pair group
    float acc[2][5][4];
#pragma unroll
    for (int r = 0; r < 2; ++r)
#pragma unroll
        for (int m = 0; m < 5; ++m)
#pragma unroll
            for (int j = 0; j < 4; ++j) acc[r][m][j] = 0.f;
#pragma unroll 2
    for (int u = 0; u < 64; ++u) {
        float c0 = bf2f(sC[(g * 2 + 0) * WB + u * 32 + b]);
        float c1 = bf2f(sC[(g * 2 + 1) * WB + u * 32 + b]);
#pragma unroll
        for (int m = 0; m < 5; ++m) {
            float4 w = *(const float4*)(sWo + (u * 5 + m) * 16 + 4 * uq);
            acc[0][m][0] += c0 * w.x; acc[0][m][1] += c0 * w.y;
            acc[0][m][2] += c0 * w.z; acc[0][m][3] += c0 * w.w;
            acc[1][m][0] += c1 * w.x; acc[1][m][1] += c1 * w.y;
            acc[1][m][2] += c1 * w.z; acc[1][m][3] += c1 * w.w;
        }
    }
#pragma unroll
    for (int r = 0; r < 2; ++r) {
        int n = n0 + g * 2 + r;
        size_t base = (size_t)n * WD + b * 16 + 4 * uq;
        *(float4*)(d0 + base) = make_float4(acc[r][0][0], acc[r][0][1], acc[r][0][2], acc[r][0][3]);
        uint2 o1, o2, o3, o4;
        o1.x = f2bf(acc[r][1][0]) | (f2bf(acc[r][1][1]) << 16);
        o1.y = f2bf(acc[r][1][2]) | (f2bf(acc[r][1][3]) << 16);
        o2.x = f2bf(acc[r][2][0]) | (f2bf(acc[r][2][1]) << 16);
        o2.y = f2bf(acc[r][2][2]) | (f2bf(acc[r][2][3]) << 16);
        o3.x = f2bf(acc[r][3][0]) | (f2bf(acc[r][3][1]) << 16);
        o3.y = f2bf(acc[r][3][2]) | (f2bf(acc[r][3][3]) << 16);
        o4.x = f2bf(acc[r][4][0]) | (f2bf(acc[r][4][1]) << 16);
        o4.y = f2bf(acc[r][4][2]) | (f2bf(acc[r][4][3]) << 16);
        *(uint2*)(dd1 + base) = o1;
        *(uint2*)(dd2 + base) = o2;
        *(uint2*)(dd3 + base) = o3;
        *(uint2*)(dd4 + base) = o4;
    }
}

// ---------- final: out = -sigmoid(theta+bl) * tanh(d0+w1+z2+w3+z4+bl) ----------
__global__ void final2_kernel(const float* __restrict__ theta, const float* __restrict__ d0,
                              const float* __restrict__ w1, const float* __restrict__ z2,
                              const float* __restrict__ w3, const float* __restrict__ z4,
                              const float* __restrict__ b_lat, float* __restrict__ out) {
    int i4 = blockIdx.x * blockDim.x + threadIdx.x;   // float4 index < NN*512/4
    size_t i = (size_t)i4 * 4;
    int u = (int)(i & 15);
    int b = (int)((i >> 4) & 31);
    int n = (int)(i >> 9);
    float4 tv = *(const float4*)(theta + i);
    float4 a0 = *(const float4*)(d0 + i);
    float4 a1 = *(const float4*)(w1 + i);
    float4 a2 = *(const float4*)(z2 + i);
    float4 a3 = *(const float4*)(w3 + i);
    float4 a4 = *(const float4*)(z4 + i);
    float4 bl = *(const float4*)(b_lat + u);
    float sx = a0.x + a1.x + a2.x + a3.x + a4.x + bl.x;
    float sy = a0.y + a1.y + a2.y + a3.y + a4.y + bl.y;
    float sz = a0.z + a1.z + a2.z + a3.z + a4.z + bl.z;
    float sw = a0.w + a1.w + a2.w + a3.w + a4.w + bl.w;
    float4 res;
    res.x = -(1.f / (1.f + expf(-(tv.x + bl.x)))) * tanhf(sx);
    res.y = -(1.f / (1.f + expf(-(tv.y + bl.y)))) * tanhf(sy);
    res.z = -(1.f / (1.f + expf(-(tv.z + bl.z)))) * tanhf(sz);
    res.w = -(1.f / (1.f + expf(-(tv.w + bl.w)))) * tanhf(sw);
    *(float4*)(out + ((size_t)b * NN + n) * 16 + u) = res;
}

extern "C" void kernel_launch(void* const* d_in, const int* in_sizes, int n_in,
                              void* d_out, int out_size, void* d_ws, size_t ws_size,
                              hipStream_t stream) {
    const float* y      = (const float*)d_in[1];
    const float* Wtheta = (const float*)d_in[2];
    const float* b_lat  = (const float*)d_in[3];
    const float* Whid   = (const float*)d_in[4];
    const float* b_hid  = (const float*)d_in[5];
    const float* Wout   = (const float*)d_in[6];
    const int*   r1     = (const int*)d_in[7];
    const int*   c1     = (const int*)d_in[8];
    const float* v1     = (const float*)d_in[9];
    const int*   r2     = (const int*)d_in[10];
    const int*   c2     = (const int*)d_in[11];
    const float* v2     = (const float*)d_in[12];
    float* out = (float*)d_out;

    // ---- workspace layout ----
    char* ws = (char*)d_ws;
    size_t off = 0;
    auto alloc = [&](size_t bytes) -> char* {
        char* p = ws + off;
        off += (bytes + 255) & ~(size_t)255;
        return p;
    };
    int*   rp1   = (int*)alloc(4097 * 4);
    int*   rp2   = (int*)alloc(4097 * 4);
    int*   cur1  = (int*)alloc(4096 * 4);            // cur1+cur2 contiguous (single memset)
    int*   cur2  = (int*)alloc(4096 * 4);
    int*   ecol1 = (int*)alloc(NNZE * 4);
    float* eval1 = (float*)alloc(NNZE * 4);
    int*   ecol2 = (int*)alloc(NNZE * 4);
    float* eval2 = (float*)alloc(NNZE * 4);
    unsigned short* xh = (unsigned short*)alloc((size_t)5 * NN * WA * 2); // 20 MB bf16 [m][n][512]
    float* theta = (float*)alloc((size_t)NN * 32 * 16 * 4);               //  8 MB
    char*  creg  = alloc((size_t)NN * WB * 2);                            // 16 MB (c bf16)
    float* d0 = (float*)alloc((size_t)NN * WD * 4);                       //  8 MB
    unsigned short* w2h = (unsigned short*)alloc((size_t)NN * WD * 2);    //  4 MB
    unsigned short* w4h = (unsigned short*)alloc((size_t)NN * WD * 2);    //  4 MB
    float* z2 = (float*)alloc((size_t)NN * WD * 4);                       //  8 MB
    float* z4 = (float*)alloc((size_t)NN * WD * 4);                       //  8 MB
    if (off > ws_size) return;   // fail loudly if ws too small

    unsigned short* x0h = xh;
    unsigned short* x1h = xh + (size_t)1 * NN * WA;
    unsigned short* x2h = xh + (size_t)2 * NN * WA;
    unsigned short* x3h = xh + (size_t)3 * NN * WA;
    unsigned short* x4h = xh + (size_t)4 * NN * WA;
    unsigned short* cbuf = (unsigned short*)creg;
    // xh dead after projA -> overlay dd1..dd4 (16 MB of 20)
    unsigned short* dd1 = (unsigned short*)((char*)xh + ((size_t)0  << 20));
    unsigned short* dd2 = (unsigned short*)((char*)xh + ((size_t)4  << 20));
    unsigned short* dd3 = (unsigned short*)((char*)xh + ((size_t)8  << 20));
    unsigned short* dd4 = (unsigned short*)((char*)xh + ((size_t)12 << 20));
    // c dead after preproj -> overlay w1/w3 (f32, final-only)
    float* w1 = (float*)creg;
    float* w3 = (float*)(creg + ((size_t)8 << 20));

    // ---- CSR build ----
    hipMemsetAsync(cur1, 0, 2 * 4096 * 4, stream);
    hist2_kernel<<<2 * NNZE / 256, 256, 0, stream>>>(r1, r2, cur1, cur2);
    scan2_kernel<<<2, 256, 0, stream>>>(cur1, rp1, cur2, rp2);
    scatter2_kernel<<<2 * NNZE / 256, 256, 0, stream>>>(r1, c1, v1, r2, c2, v2,
                                                        cur1, cur2, ecol1, eval1, ecol2, eval2);

    // ---- pass A: transpose (bf16), 2 narrow spmm launches, projection ----
    transA_kernel<<<NN, 128, 0, stream>>>(y, x0h);
    {   // x1 = S1@x0, x3 = S2@x0
        SpmmDesc a0 = { x0h, nullptr, nullptr, x1h, rp1, ecol1, eval1, 1.f, 0.f };
        SpmmDesc a1 = { x0h, nullptr, nullptr, x3h, rp2, ecol2, eval2, 1.f, 0.f };
        spmmD_kernel<<<2 * NN, 64, 0, stream>>>(a0, a1, a0, a1, 2);
    }
    {   // x2 = 2*S1@x1 - x0, x4 = 2*S2@x3 - x0
        SpmmDesc a0 = { x1h, x0h, nullptr, x2h, rp1, ecol1, eval1, 2.f, -1.f };
        SpmmDesc a1 = { x3h, x0h, nullptr, x4h, rp2, ecol2, eval2, 2.f, -1.f };
        spmmD_kernel<<<2 * NN, 64, 0, stream>>>(a0, a1, a0, a1, 2);
    }
    projA_kernel<<<NN / 2, 256, 0, stream>>>(xh, Wtheta, Whid, b_hid, theta, cbuf);

    // ---- pass B (commuted): pre-project, then narrow diffusions ----
    preproj_kernel<<<NN / 4, 256, 0, stream>>>(cbuf, Wout, d0, dd1, dd2, dd3, dd4);
    {   // w1=S1@d1 (f32), w2=S1@d2 (bf16), w3=S2@d3 (f32), w4=S2@d4 (bf16)
        SpmmDesc a0 = { dd1, nullptr, w1, nullptr, rp1, ecol1, eval1, 1.f, 0.f };
        SpmmDesc a1 = { dd2, nullptr, nullptr, w2h, rp1, ecol1, eval1, 1.f, 0.f };
        SpmmDesc a2 = { dd3, nullptr, w3, nullptr, rp2, ecol2, eval2, 1.f, 0.f };
        SpmmDesc a3 = { dd4, nullptr, nullptr, w4h, rp2, ecol2, eval2, 1.f, 0.f };
        spmmD_kernel<<<4 * NN, 64, 0, stream>>>(a0, a1, a2, a3, 4);
    }
    {   // z2 = 2*S1@w2 - d2 (f32), z4 = 2*S2@w4 - d4 (f32)
        SpmmDesc b0 = { w2h, dd2, z2, nullptr, rp1, ecol1, eval1, 2.f, -1.f };
        SpmmDesc b1 = { w4h, dd4, z4, nullptr, rp2, ecol2, eval2, 2.f, -1.f };
        spmmD_kernel<<<2 * NN, 64, 0, stream>>>(b0, b1, b0, b1, 2);
    }

    // ---- epilogue ----
    final2_kernel<<<(NN * WD) / 4 / 256, 256, 0, stream>>>(theta, d0, w1, z2, w3, z4, b_lat, out);
}

// Round 5
// 219.426 us; speedup vs baseline: 1.9647x; 1.1921x over previous
//
#include <hip/hip_runtime.h>
#include <stdint.h>

// N=4096, B=32, LATENT=16, UNITS=64, NNZ=65536, K=2, M=5.
#define NN    4096
#define BB    32
#define NNZE  65536
#define WA    512      // pass-A diffusion width (16*B), row layout [b*16+f]
#define WB    2048     // c width (b*64+u), bf16
#define WD    512      // pass-B diffusion width (16*B), row layout [b*16+u']

typedef __attribute__((ext_vector_type(8))) short bf16x8;
typedef __attribute__((ext_vector_type(4))) float f32x4;

// ---------- bf16 helpers ----------
__device__ __forceinline__ float bf2f(unsigned int h) {
    union { unsigned int u; float f; } c; c.u = h << 16; return c.f;
}
__device__ __forceinline__ unsigned int f2bf(float f) {
    union { float ff; unsigned int u; } c; c.ff = f;
    return (c.u + 0x7fffu + ((c.u >> 16) & 1u)) >> 16;
}

// ---------- CSR build (both supports per launch) ----------
__global__ void hist2_kernel(const int* __restrict__ r1, const int* __restrict__ r2,
                             int* __restrict__ cnt1, int* __restrict__ cnt2) {
    int e = blockIdx.x * blockDim.x + threadIdx.x;   // < 2*NNZE
    if (e < NNZE) atomicAdd(&cnt1[r1[e]], 1);
    else          atomicAdd(&cnt2[r2[e - NNZE]], 1);
}

__global__ void scan2_kernel(int* cur1, int* rp1, int* cur2, int* rp2) {
    int* cur = (blockIdx.x == 0) ? cur1 : cur2;
    int* rp  = (blockIdx.x == 0) ? rp1  : rp2;
    __shared__ int part[256];
    int t = threadIdx.x;
    int base = t * 16;
    int loc[16];
    int s = 0;
#pragma unroll
    for (int i = 0; i < 16; ++i) { loc[i] = s; s += cur[base + i]; }
    part[t] = s;
    __syncthreads();
    for (int off = 1; off < 256; off <<= 1) {
        int v = 0;
        if (t >= off) v = part[t - off];
        __syncthreads();
        part[t] += v;
        __syncthreads();
    }
    int excl = (t == 0) ? 0 : part[t - 1];
#pragma unroll
    for (int i = 0; i < 16; ++i) rp[base + i] = excl + loc[i];
    __syncthreads();
#pragma unroll
    for (int i = 0; i < 16; ++i) cur[base + i] = rp[base + i];
    if (t == 255) rp[4096] = part[255];
}

__global__ void scatter2_kernel(const int* __restrict__ r1, const int* __restrict__ c1, const float* __restrict__ v1,
                                const int* __restrict__ r2, const int* __restrict__ c2, const float* __restrict__ v2,
                                int* __restrict__ cur1, int* __restrict__ cur2,
                                int* __restrict__ ecol1, float* __restrict__ eval1,
                                int* __restrict__ ecol2, float* __restrict__ eval2) {
    int e = blockIdx.x * blockDim.x + threadIdx.x;
    if (e < NNZE) {
        int pos = atomicAdd(&cur1[r1[e]], 1);
        ecol1[pos] = c1[e]; eval1[pos] = v1[e];
    } else {
        int ee = e - NNZE;
        int pos = atomicAdd(&cur2[r2[ee]], 1);
        ecol2[pos] = c2[ee]; eval2[pos] = v2[ee];
    }
}

// ---------- transpose y -> x0 row layout [n][b*16+f], bf16 (no LDS) ----------
__global__ void transA_kernel(const float* __restrict__ y, unsigned short* __restrict__ x0h) {
    int t = threadIdx.x, n = blockIdx.x;   // 128 threads
    int b = t & 31, q = t >> 5;
    float4 y4 = *(const float4*)(y + (size_t)b * (NN * 16) + n * 16 + 4 * q);
    uint2 o;
    o.x = f2bf(y4.x) | (f2bf(y4.y) << 16);
    o.y = f2bf(y4.z) | (f2bf(y4.w) << 16);
    *(uint2*)(x0h + (size_t)n * WA + b * 16 + 4 * q) = o;
}

// ---------- spmmD: 512-wide bf16 spmm, multi-instance, XCD-chunked ----------
struct SpmmDesc {
    const unsigned short* in;     // [NN][512] bf16
    const unsigned short* prev;   // nullptr if beta==0
    float* outF;                  // exactly one of outF/outH non-null
    unsigned short* outH;
    const int* rp; const int* ecol; const float* eval;
    float alpha, beta;
};

__launch_bounds__(64)
__global__ void spmmD_kernel(SpmmDesc q0, SpmmDesc q1, SpmmDesc q2, SpmmDesc q3, int ninst) {
    __shared__ int scol[64];
    __shared__ float sval[64];
    int blk = blockIdx.x;
    int xcd = blk & 7;
    int idx = blk >> 3;
    int spx = 8 / ninst;                 // XCD slots per instance
    int inst = xcd / spx;                // each instance's 4MB source stays L2-resident per XCD
    int sub  = xcd - inst * spx;
    int row  = sub * (NN / spx) + idx;   // bijective over (inst,row)
    SpmmDesc q = (inst == 0) ? q0 : (inst == 1) ? q1 : (inst == 2) ? q2 : q3;
    int t = threadIdx.x;   // 64 threads, uint4 (8 bf16) each
    int beg = q.rp[row], end = q.rp[row + 1];
    float acc[8];
#pragma unroll
    for (int k = 0; k < 8; ++k) acc[k] = 0.f;
    for (int i0 = beg; i0 < end; i0 += 64) {
        int nn = end - i0; if (nn > 64) nn = 64;
        __syncthreads();
        if (t < nn) { scol[t] = q.ecol[i0 + t]; sval[t] = q.eval[i0 + t]; }
        __syncthreads();
#pragma unroll 4
        for (int j = 0; j < nn; ++j) {
            uint4 xv = ((const uint4*)(q.in + (size_t)scol[j] * WD))[t];
            float v = sval[j];
            acc[0] += v * bf2f(xv.x & 0xffffu);
            acc[1] += v * bf2f(xv.x >> 16);
            acc[2] += v * bf2f(xv.y & 0xffffu);
            acc[3] += v * bf2f(xv.y >> 16);
            acc[4] += v * bf2f(xv.z & 0xffffu);
            acc[5] += v * bf2f(xv.z >> 16);
            acc[6] += v * bf2f(xv.w & 0xffffu);
            acc[7] += v * bf2f(xv.w >> 16);
        }
    }
    float r[8];
#pragma unroll
    for (int k = 0; k < 8; ++k) r[k] = q.alpha * acc[k];
    if (q.prev) {
        uint4 pv = ((const uint4*)(q.prev + (size_t)row * WD))[t];
        r[0] += q.beta * bf2f(pv.x & 0xffffu);
        r[1] += q.beta * bf2f(pv.x >> 16);
        r[2] += q.beta * bf2f(pv.y & 0xffffu);
        r[3] += q.beta * bf2f(pv.y >> 16);
        r[4] += q.beta * bf2f(pv.z & 0xffffu);
        r[5] += q.beta * bf2f(pv.z >> 16);
        r[6] += q.beta * bf2f(pv.w & 0xffffu);
        r[7] += q.beta * bf2f(pv.w >> 16);
    }
    if (q.outF) {
        float* po = q.outF + (size_t)row * WD + t * 8;
        *(float4*)(po)     = make_float4(r[0], r[1], r[2], r[3]);
        *(float4*)(po + 4) = make_float4(r[4], r[5], r[6], r[7]);
    } else {
        uint4 o;
        o.x = f2bf(r[0]) | (f2bf(r[1]) << 16);
        o.y = f2bf(r[2]) | (f2bf(r[3]) << 16);
        o.z = f2bf(r[4]) | (f2bf(r[5]) << 16);
        o.w = f2bf(r[6]) | (f2bf(r[7]) << 16);
        ((uint4*)(q.outH + (size_t)row * WD))[t] = o;
    }
}

// ---------- projA via MFMA: [32 b][80 k(m*16+f)] @ W[80][80] per n ----------
// k-slot convention: k = kt*32 + g*8 + j (g=lane>>4, j=elem). Same map used for
// A (contiguous 16B global load) and B (LDS-staged W^T) -> permutation-safe.
// D layout (verified): col = lane&15, row = g*4 + reg.
__launch_bounds__(256)
__global__ void projA_mfma(const unsigned short* __restrict__ xh,   // [5][NN][b*16+f] bf16
                           const float* __restrict__ Wtheta, const float* __restrict__ Whid,
                           const float* __restrict__ b_hid,
                           float* __restrict__ theta,               // [NN][b*16+u']
                           unsigned short* __restrict__ c) {        // [NN][b*64+u] bf16
    __shared__ __align__(16) unsigned short sW[80 * 104];   // [col][k], pad 104 (16.6 KB)
    int t = threadIdx.x;
    // stage W bf16 as [col][k=m*16+f]; k in [80,96) zero (K padded to 96)
    for (int i = t; i < 80 * 96; i += 256) {
        int col = i / 96, k = i - col * 96;
        int m = k >> 4, f = k & 15;
        float v = 0.f;
        if (m < 5) v = (col < 16) ? Wtheta[(f * 5 + m) * 16 + col]
                                  : Whid[(f * 5 + m) * 64 + (col - 16)];
        sW[col * 104 + k] = (unsigned short)f2bf(v);
    }
    __syncthreads();
    int lane = t & 63, w = t >> 6;
    int r = lane & 15, g = lane >> 4;
    bf16x8 wf[5][3];
#pragma unroll
    for (int ct = 0; ct < 5; ++ct)
#pragma unroll
        for (int kt = 0; kt < 3; ++kt)
            wf[ct][kt] = *(const bf16x8*)(sW + (ct * 16 + r) * 104 + kt * 32 + g * 8);
    float bh[4];
#pragma unroll
    for (int ct = 0; ct < 4; ++ct) bh[ct] = b_hid[ct * 16 + r];

    for (int i = 0; i < 2; ++i) {
        int n = blockIdx.x * 8 + w * 2 + i;
        f32x4 acc[2][5];
#pragma unroll
        for (int bt = 0; bt < 2; ++bt)
#pragma unroll
            for (int ct = 0; ct < 5; ++ct)
                acc[bt][ct] = (f32x4){0.f, 0.f, 0.f, 0.f};
#pragma unroll
        for (int kt = 0; kt < 3; ++kt) {
            bf16x8 a[2];
            int m = kt * 2 + (g >> 1);
#pragma unroll
            for (int bt = 0; bt < 2; ++bt) {
                bf16x8 av = {0, 0, 0, 0, 0, 0, 0, 0};
                if (m < 5)
                    av = *(const bf16x8*)(xh + ((size_t)m * NN + n) * WA
                                          + (bt * 16 + r) * 16 + (g & 1) * 8);
                a[bt] = av;
            }
#pragma unroll
            for (int bt = 0; bt < 2; ++bt)
#pragma unroll
                for (int ct = 0; ct < 5; ++ct)
                    acc[bt][ct] = __builtin_amdgcn_mfma_f32_16x16x32_bf16(
                        a[bt], wf[ct][kt], acc[bt][ct], 0, 0, 0);
        }
#pragma unroll
        for (int bt = 0; bt < 2; ++bt) {
#pragma unroll
            for (int reg = 0; reg < 4; ++reg) {
                int b = bt * 16 + g * 4 + reg;
                theta[(size_t)n * 512 + b * 16 + r] = acc[bt][0][reg];
            }
#pragma unroll
            for (int ct = 1; ct < 5; ++ct) {
                int u = (ct - 1) * 16 + r;
#pragma unroll
                for (int reg = 0; reg < 4; ++reg) {
                    int b = bt * 16 + g * 4 + reg;
                    float hv = tanhf(acc[bt][ct][reg] + bh[ct - 1]);
                    c[(size_t)n * WB + b * 64 + u] = (unsigned short)f2bf(hv);
                }
            }
        }
    }
}

// ---------- preproj via MFMA: [32 b][64 u] @ Wout[64][80 (m*16+u')] per n ----------
__launch_bounds__(256)
__global__ void preproj_mfma(const unsigned short* __restrict__ c,  // [NN][b*64+u] bf16
                             const float* __restrict__ Wout,        // [(u*5+m)*16+u']
                             float* __restrict__ d0,
                             unsigned short* __restrict__ dd1, unsigned short* __restrict__ dd2,
                             unsigned short* __restrict__ dd3, unsigned short* __restrict__ dd4) {
    __shared__ __align__(16) unsigned short sW[80 * 72];    // [col=m*16+u'][k=u] (11.3 KB)
    int t = threadIdx.x;
    for (int i = t; i < 80 * 64; i += 256) {
        int col = i >> 6, k = i & 63;
        int m = col >> 4, up = col & 15;
        sW[col * 72 + k] = (unsigned short)f2bf(Wout[(k * 5 + m) * 16 + up]);
    }
    __syncthreads();
    int lane = t & 63, w = t >> 6;
    int r = lane & 15, g = lane >> 4;
    bf16x8 wf[5][2];
#pragma unroll
    for (int ct = 0; ct < 5; ++ct)
#pragma unroll
        for (int kt = 0; kt < 2; ++kt)
            wf[ct][kt] = *(const bf16x8*)(sW + (ct * 16 + r) * 72 + kt * 32 + g * 8);

    for (int i = 0; i < 2; ++i) {
        int n = blockIdx.x * 8 + w * 2 + i;
        f32x4 acc[2][5];
#pragma unroll
        for (int bt = 0; bt < 2; ++bt)
#pragma unroll
            for (int ct = 0; ct < 5; ++ct)
                acc[bt][ct] = (f32x4){0.f, 0.f, 0.f, 0.f};
#pragma unroll
        for (int kt = 0; kt < 2; ++kt) {
            bf16x8 a[2];
#pragma unroll
            for (int bt = 0; bt < 2; ++bt)
                a[bt] = *(const bf16x8*)(c + (size_t)n * WB + (bt * 16 + r) * 64
                                         + kt * 32 + g * 8);
#pragma unroll
            for (int bt = 0; bt < 2; ++bt)
#pragma unroll
                for (int ct = 0; ct < 5; ++ct)
                    acc[bt][ct] = __builtin_amdgcn_mfma_f32_16x16x32_bf16(
                        a[bt], wf[ct][kt], acc[bt][ct], 0, 0, 0);
        }
#pragma unroll
        for (int bt = 0; bt < 2; ++bt) {
#pragma unroll
            for (int reg = 0; reg < 4; ++reg) {
                int b = bt * 16 + g * 4 + reg;
                d0[(size_t)n * WD + b * 16 + r] = acc[bt][0][reg];
            }
#pragma unroll
            for (int ct = 1; ct < 5; ++ct) {
                unsigned short* dp = (ct == 1) ? dd1 : (ct == 2) ? dd2 : (ct == 3) ? dd3 : dd4;
#pragma unroll
                for (int reg = 0; reg < 4; ++reg) {
                    int b = bt * 16 + g * 4 + reg;
                    dp[(size_t)n * WD + b * 16 + r] = (unsigned short)f2bf(acc[bt][ct][reg]);
                }
            }
        }
    }
}

// ---------- final: out = -sigmoid(theta+bl) * tanh(d0+w1+z2+w3+z4+bl) ----------
__global__ void final2_kernel(const float* __restrict__ theta, const float* __restrict__ d0,
                              const float* __restrict__ w1, const float* __restrict__ z2,
                              const float* __restrict__ w3, const float* __restrict__ z4,
                              const float* __restrict__ b_lat, float* __restrict__ out) {
    int i4 = blockIdx.x * blockDim.x + threadIdx.x;   // float4 index < NN*512/4
    size_t i = (size_t)i4 * 4;
    int u = (int)(i & 15);
    int b = (int)((i >> 4) & 31);
    int n = (int)(i >> 9);
    float4 tv = *(const float4*)(theta + i);
    float4 a0 = *(const float4*)(d0 + i);
    float4 a1 = *(const float4*)(w1 + i);
    float4 a2 = *(const float4*)(z2 + i);
    float4 a3 = *(const float4*)(w3 + i);
    float4 a4 = *(const float4*)(z4 + i);
    float4 bl = *(const float4*)(b_lat + u);
    float sx = a0.x + a1.x + a2.x + a3.x + a4.x + bl.x;
    float sy = a0.y + a1.y + a2.y + a3.y + a4.y + bl.y;
    float sz = a0.z + a1.z + a2.z + a3.z + a4.z + bl.z;
    float sw = a0.w + a1.w + a2.w + a3.w + a4.w + bl.w;
    float4 res;
    res.x = -(1.f / (1.f + expf(-(tv.x + bl.x)))) * tanhf(sx);
    res.y = -(1.f / (1.f + expf(-(tv.y + bl.y)))) * tanhf(sy);
    res.z = -(1.f / (1.f + expf(-(tv.z + bl.z)))) * tanhf(sz);
    res.w = -(1.f / (1.f + expf(-(tv.w + bl.w)))) * tanhf(sw);
    *(float4*)(out + ((size_t)b * NN + n) * 16 + u) = res;
}

extern "C" void kernel_launch(void* const* d_in, const int* in_sizes, int n_in,
                              void* d_out, int out_size, void* d_ws, size_t ws_size,
                              hipStream_t stream) {
    const float* y      = (const float*)d_in[1];
    const float* Wtheta = (const float*)d_in[2];
    const float* b_lat  = (const float*)d_in[3];
    const float* Whid   = (const float*)d_in[4];
    const float* b_hid  = (const float*)d_in[5];
    const float* Wout   = (const float*)d_in[6];
    const int*   r1     = (const int*)d_in[7];
    const int*   c1     = (const int*)d_in[8];
    const float* v1     = (const float*)d_in[9];
    const int*   r2     = (const int*)d_in[10];
    const int*   c2     = (const int*)d_in[11];
    const float* v2     = (const float*)d_in[12];
    float* out = (float*)d_out;

    // ---- workspace layout ----
    char* ws = (char*)d_ws;
    size_t off = 0;
    auto alloc = [&](size_t bytes) -> char* {
        char* p = ws + off;
        off += (bytes + 255) & ~(size_t)255;
        return p;
    };
    int*   rp1   = (int*)alloc(4097 * 4);
    int*   rp2   = (int*)alloc(4097 * 4);
    int*   cur1  = (int*)alloc(4096 * 4);            // cur1+cur2 contiguous (single memset)
    int*   cur2  = (int*)alloc(4096 * 4);
    int*   ecol1 = (int*)alloc(NNZE * 4);
    float* eval1 = (float*)alloc(NNZE * 4);
    int*   ecol2 = (int*)alloc(NNZE * 4);
    float* eval2 = (float*)alloc(NNZE * 4);
    unsigned short* xh = (unsigned short*)alloc((size_t)5 * NN * WA * 2); // 20 MB bf16 [m][n][512]
    float* theta = (float*)alloc((size_t)NN * 512 * 4);                   //  8 MB
    char*  creg  = alloc((size_t)NN * WB * 2);                            // 16 MB (c bf16)
    float* d0 = (float*)alloc((size_t)NN * WD * 4);                       //  8 MB
    unsigned short* w2h = (unsigned short*)alloc((size_t)NN * WD * 2);    //  4 MB
    unsigned short* w4h = (unsigned short*)alloc((size_t)NN * WD * 2);    //  4 MB
    float* z2 = (float*)alloc((size_t)NN * WD * 4);                       //  8 MB
    float* z4 = (float*)alloc((size_t)NN * WD * 4);                       //  8 MB
    if (off > ws_size) return;   // fail loudly if ws too small

    unsigned short* x0h = xh;
    unsigned short* x1h = xh + (size_t)1 * NN * WA;
    unsigned short* x2h = xh + (size_t)2 * NN * WA;
    unsigned short* x3h = xh + (size_t)3 * NN * WA;
    unsigned short* x4h = xh + (size_t)4 * NN * WA;
    unsigned short* cbuf = (unsigned short*)creg;
    // xh dead after projA -> overlay dd1..dd4 (16 MB of 20)
    unsigned short* dd1 = (unsigned short*)((char*)xh + ((size_t)0  << 20));
    unsigned short* dd2 = (unsigned short*)((char*)xh + ((size_t)4  << 20));
    unsigned short* dd3 = (unsigned short*)((char*)xh + ((size_t)8  << 20));
    unsigned short* dd4 = (unsigned short*)((char*)xh + ((size_t)12 << 20));
    // c dead after preproj -> overlay w1/w3 (f32, final-only)
    float* w1 = (float*)creg;
    float* w3 = (float*)(creg + ((size_t)8 << 20));

    // ---- CSR build ----
    hipMemsetAsync(cur1, 0, 2 * 4096 * 4, stream);
    hist2_kernel<<<2 * NNZE / 256, 256, 0, stream>>>(r1, r2, cur1, cur2);
    scan2_kernel<<<2, 256, 0, stream>>>(cur1, rp1, cur2, rp2);
    scatter2_kernel<<<2 * NNZE / 256, 256, 0, stream>>>(r1, c1, v1, r2, c2, v2,
                                                        cur1, cur2, ecol1, eval1, ecol2, eval2);

    // ---- pass A: transpose (bf16, [b*16+f]), 2 narrow spmm launches, MFMA projection ----
    transA_kernel<<<NN, 128, 0, stream>>>(y, x0h);
    {   // x1 = S1@x0, x3 = S2@x0
        SpmmDesc a0 = { x0h, nullptr, nullptr, x1h, rp1, ecol1, eval1, 1.f, 0.f };
        SpmmDesc a1 = { x0h, nullptr, nullptr, x3h, rp2, ecol2, eval2, 1.f, 0.f };
        spmmD_kernel<<<2 * NN, 64, 0, stream>>>(a0, a1, a0, a1, 2);
    }
    {   // x2 = 2*S1@x1 - x0, x4 = 2*S2@x3 - x0
        SpmmDesc a0 = { x1h, x0h, nullptr, x2h, rp1, ecol1, eval1, 2.f, -1.f };
        SpmmDesc a1 = { x3h, x0h, nullptr, x4h, rp2, ecol2, eval2, 2.f, -1.f };
        spmmD_kernel<<<2 * NN, 64, 0, stream>>>(a0, a1, a0, a1, 2);
    }
    projA_mfma<<<NN / 8, 256, 0, stream>>>(xh, Wtheta, Whid, b_hid, theta, cbuf);

    // ---- pass B (commuted): MFMA pre-projection, then narrow diffusions ----
    preproj_mfma<<<NN / 8, 256, 0, stream>>>(cbuf, Wout, d0, dd1, dd2, dd3, dd4);
    {   // w1=S1@d1 (f32), w2=S1@d2 (bf16), w3=S2@d3 (f32), w4=S2@d4 (bf16)
        SpmmDesc a0 = { dd1, nullptr, w1, nullptr, rp1, ecol1, eval1, 1.f, 0.f };
        SpmmDesc a1 = { dd2, nullptr, nullptr, w2h, rp1, ecol1, eval1, 1.f, 0.f };
        SpmmDesc a2 = { dd3, nullptr, w3, nullptr, rp2, ecol2, eval2, 1.f, 0.f };
        SpmmDesc a3 = { dd4, nullptr, nullptr, w4h, rp2, ecol2, eval2, 1.f, 0.f };
        spmmD_kernel<<<4 * NN, 64, 0, stream>>>(a0, a1, a2, a3, 4);
    }
    {   // z2 = 2*S1@w2 - d2 (f32), z4 = 2*S2@w4 - d4 (f32)
        SpmmDesc b0 = { w2h, dd2, z2, nullptr, rp1, ecol1, eval1, 2.f, -1.f };
        SpmmDesc b1 = { w4h, dd4, z4, nullptr, rp2, ecol2, eval2, 2.f, -1.f };
        spmmD_kernel<<<2 * NN, 64, 0, stream>>>(b0, b1, b0, b1, 2);
    }

    // ---- epilogue ----
    final2_kernel<<<(NN * WD) / 4 / 256, 256, 0, stream>>>(theta, d0, w1, z2, w3, z4, b_lat, out);
}

// Round 6
// 208.332 us; speedup vs baseline: 2.0693x; 1.0533x over previous
//
#include <hip/hip_runtime.h>
#include <stdint.h>

// N=4096, B=32, LATENT=16, UNITS=64, NNZ=65536, K=2, M=5.
#define NN    4096
#define BB    32
#define NNZE  65536
#define WA    512      // pass-A diffusion width (16*B), row layout [b*16+f]
#define WB    2048     // c width (b*64+u), bf16
#define WD    512      // pass-B diffusion width (16*B), row layout [b*16+u']

typedef __attribute__((ext_vector_type(8))) short bf16x8;
typedef __attribute__((ext_vector_type(4))) float f32x4;

// ---------- bf16 helpers ----------
__device__ __forceinline__ float bf2f(unsigned int h) {
    union { unsigned int u; float f; } c; c.u = h << 16; return c.f;
}
__device__ __forceinline__ unsigned int f2bf(float f) {
    union { float ff; unsigned int u; } c; c.ff = f;
    return (c.u + 0x7fffu + ((c.u >> 16) & 1u)) >> 16;
}

// ---------- CSR build (both supports per launch) ----------
__global__ void hist2_kernel(const int* __restrict__ r1, const int* __restrict__ r2,
                             int* __restrict__ cnt1, int* __restrict__ cnt2) {
    int e = blockIdx.x * blockDim.x + threadIdx.x;   // < 2*NNZE
    if (e < NNZE) atomicAdd(&cnt1[r1[e]], 1);
    else          atomicAdd(&cnt2[r2[e - NNZE]], 1);
}

__global__ void scan2_kernel(int* cur1, int* rp1, int* cur2, int* rp2) {
    int* cur = (blockIdx.x == 0) ? cur1 : cur2;
    int* rp  = (blockIdx.x == 0) ? rp1  : rp2;
    __shared__ int part[256];
    int t = threadIdx.x;
    int base = t * 16;
    int loc[16];
    int s = 0;
#pragma unroll
    for (int i = 0; i < 16; ++i) { loc[i] = s; s += cur[base + i]; }
    part[t] = s;
    __syncthreads();
    for (int off = 1; off < 256; off <<= 1) {
        int v = 0;
        if (t >= off) v = part[t - off];
        __syncthreads();
        part[t] += v;
        __syncthreads();
    }
    int excl = (t == 0) ? 0 : part[t - 1];
#pragma unroll
    for (int i = 0; i < 16; ++i) rp[base + i] = excl + loc[i];
    __syncthreads();
#pragma unroll
    for (int i = 0; i < 16; ++i) cur[base + i] = rp[base + i];
    if (t == 255) rp[4096] = part[255];
}

__global__ void scatter2_kernel(const int* __restrict__ r1, const int* __restrict__ c1, const float* __restrict__ v1,
                                const int* __restrict__ r2, const int* __restrict__ c2, const float* __restrict__ v2,
                                int* __restrict__ cur1, int* __restrict__ cur2,
                                int* __restrict__ ecol1, float* __restrict__ eval1,
                                int* __restrict__ ecol2, float* __restrict__ eval2) {
    int e = blockIdx.x * blockDim.x + threadIdx.x;
    if (e < NNZE) {
        int pos = atomicAdd(&cur1[r1[e]], 1);
        ecol1[pos] = c1[e]; eval1[pos] = v1[e];
    } else {
        int ee = e - NNZE;
        int pos = atomicAdd(&cur2[r2[ee]], 1);
        ecol2[pos] = c2[ee]; eval2[pos] = v2[ee];
    }
}

// ---------- transpose y -> x0 row layout [n][b*16+f], bf16 (no LDS) ----------
__global__ void transA_kernel(const float* __restrict__ y, unsigned short* __restrict__ x0h) {
    int t = threadIdx.x, n = blockIdx.x;   // 128 threads
    int b = t & 31, q = t >> 5;
    float4 y4 = *(const float4*)(y + (size_t)b * (NN * 16) + n * 16 + 4 * q);
    uint2 o;
    o.x = f2bf(y4.x) | (f2bf(y4.y) << 16);
    o.y = f2bf(y4.z) | (f2bf(y4.w) << 16);
    *(uint2*)(x0h + (size_t)n * WA + b * 16 + 4 * q) = o;
}

// ---------- spmmD: 512-wide bf16 spmm, multi-instance, XCD-chunked ----------
struct SpmmDesc {
    const unsigned short* in;     // [NN][512] bf16
    const unsigned short* prev;   // nullptr if beta==0
    float* outF;                  // exactly one of outF/outH non-null
    unsigned short* outH;
    const int* rp; const int* ecol; const float* eval;
    float alpha, beta;
};

__launch_bounds__(64)
__global__ void spmmD_kernel(SpmmDesc q0, SpmmDesc q1, SpmmDesc q2, SpmmDesc q3, int ninst) {
    __shared__ int scol[64];
    __shared__ float sval[64];
    int blk = blockIdx.x;
    int xcd = blk & 7;
    int idx = blk >> 3;
    int spx = 8 / ninst;                 // XCD slots per instance
    int inst = xcd / spx;                // each instance's 4MB source stays L2-resident per XCD
    int sub  = xcd - inst * spx;
    int row  = sub * (NN / spx) + idx;   // bijective over (inst,row)
    SpmmDesc q = (inst == 0) ? q0 : (inst == 1) ? q1 : (inst == 2) ? q2 : q3;
    int t = threadIdx.x;   // 64 threads, uint4 (8 bf16) each
    int beg = q.rp[row], end = q.rp[row + 1];
    float acc[8];
#pragma unroll
    for (int k = 0; k < 8; ++k) acc[k] = 0.f;
    for (int i0 = beg; i0 < end; i0 += 64) {
        int nn = end - i0; if (nn > 64) nn = 64;
        __syncthreads();
        if (t < nn) { scol[t] = q.ecol[i0 + t]; sval[t] = q.eval[i0 + t]; }
        __syncthreads();
#pragma unroll 4
        for (int j = 0; j < nn; ++j) {
            uint4 xv = ((const uint4*)(q.in + (size_t)scol[j] * WD))[t];
            float v = sval[j];
            acc[0] += v * bf2f(xv.x & 0xffffu);
            acc[1] += v * bf2f(xv.x >> 16);
            acc[2] += v * bf2f(xv.y & 0xffffu);
            acc[3] += v * bf2f(xv.y >> 16);
            acc[4] += v * bf2f(xv.z & 0xffffu);
            acc[5] += v * bf2f(xv.z >> 16);
            acc[6] += v * bf2f(xv.w & 0xffffu);
            acc[7] += v * bf2f(xv.w >> 16);
        }
    }
    float r[8];
#pragma unroll
    for (int k = 0; k < 8; ++k) r[k] = q.alpha * acc[k];
    if (q.prev) {
        uint4 pv = ((const uint4*)(q.prev + (size_t)row * WD))[t];
        r[0] += q.beta * bf2f(pv.x & 0xffffu);
        r[1] += q.beta * bf2f(pv.x >> 16);
        r[2] += q.beta * bf2f(pv.y & 0xffffu);
        r[3] += q.beta * bf2f(pv.y >> 16);
        r[4] += q.beta * bf2f(pv.z & 0xffffu);
        r[5] += q.beta * bf2f(pv.z >> 16);
        r[6] += q.beta * bf2f(pv.w & 0xffffu);
        r[7] += q.beta * bf2f(pv.w >> 16);
    }
    if (q.outF) {
        float* po = q.outF + (size_t)row * WD + t * 8;
        *(float4*)(po)     = make_float4(r[0], r[1], r[2], r[3]);
        *(float4*)(po + 4) = make_float4(r[4], r[5], r[6], r[7]);
    } else {
        uint4 o;
        o.x = f2bf(r[0]) | (f2bf(r[1]) << 16);
        o.y = f2bf(r[2]) | (f2bf(r[3]) << 16);
        o.z = f2bf(r[4]) | (f2bf(r[5]) << 16);
        o.w = f2bf(r[6]) | (f2bf(r[7]) << 16);
        ((uint4*)(q.outH + (size_t)row * WD))[t] = o;
    }
}

// ---------- projA via MFMA: [32 b][80 k(m*16+f)] @ W[80][80] per n ----------
// k-slot convention: k = kt*32 + g*8 + j (g=lane>>4, j=elem). Same map used for
// A (contiguous 16B global load) and B (LDS-staged W^T) -> permutation-safe.
// D layout (verified): col = lane&15, row = g*4 + reg.
__launch_bounds__(256)
__global__ void projA_mfma(const unsigned short* __restrict__ xh,   // [5][NN][b*16+f] bf16
                           const float* __restrict__ Wtheta, const float* __restrict__ Whid,
                           const float* __restrict__ b_hid,
                           float* __restrict__ theta,               // [NN][b*16+u']
                           unsigned short* __restrict__ c) {        // [NN][b*64+u] bf16
    __shared__ __align__(16) unsigned short sW[80 * 104];   // [col][k], pad 104 (16.6 KB)
    int t = threadIdx.x;
    // stage W bf16 as [col][k=m*16+f]; k in [80,96) zero (K padded to 96)
    for (int i = t; i < 80 * 96; i += 256) {
        int col = i / 96, k = i - col * 96;
        int m = k >> 4, f = k & 15;
        float v = 0.f;
        if (m < 5) v = (col < 16) ? Wtheta[(f * 5 + m) * 16 + col]
                                  : Whid[(f * 5 + m) * 64 + (col - 16)];
        sW[col * 104 + k] = (unsigned short)f2bf(v);
    }
    __syncthreads();
    int lane = t & 63, w = t >> 6;
    int r = lane & 15, g = lane >> 4;
    bf16x8 wf[5][3];
#pragma unroll
    for (int ct = 0; ct < 5; ++ct)
#pragma unroll
        for (int kt = 0; kt < 3; ++kt)
            wf[ct][kt] = *(const bf16x8*)(sW + (ct * 16 + r) * 104 + kt * 32 + g * 8);
    float bh[4];
#pragma unroll
    for (int ct = 0; ct < 4; ++ct) bh[ct] = b_hid[ct * 16 + r];

    for (int i = 0; i < 2; ++i) {
        int n = blockIdx.x * 8 + w * 2 + i;
        f32x4 acc[2][5];
#pragma unroll
        for (int bt = 0; bt < 2; ++bt)
#pragma unroll
            for (int ct = 0; ct < 5; ++ct)
                acc[bt][ct] = (f32x4){0.f, 0.f, 0.f, 0.f};
#pragma unroll
        for (int kt = 0; kt < 3; ++kt) {
            bf16x8 a[2];
            int m = kt * 2 + (g >> 1);
#pragma unroll
            for (int bt = 0; bt < 2; ++bt) {
                bf16x8 av = {0, 0, 0, 0, 0, 0, 0, 0};
                if (m < 5)
                    av = *(const bf16x8*)(xh + ((size_t)m * NN + n) * WA
                                          + (bt * 16 + r) * 16 + (g & 1) * 8);
                a[bt] = av;
            }
#pragma unroll
            for (int bt = 0; bt < 2; ++bt)
#pragma unroll
                for (int ct = 0; ct < 5; ++ct)
                    acc[bt][ct] = __builtin_amdgcn_mfma_f32_16x16x32_bf16(
                        a[bt], wf[ct][kt], acc[bt][ct], 0, 0, 0);
        }
#pragma unroll
        for (int bt = 0; bt < 2; ++bt) {
#pragma unroll
            for (int reg = 0; reg < 4; ++reg) {
                int b = bt * 16 + g * 4 + reg;
                theta[(size_t)n * 512 + b * 16 + r] = acc[bt][0][reg];
            }
#pragma unroll
            for (int ct = 1; ct < 5; ++ct) {
                int u = (ct - 1) * 16 + r;
#pragma unroll
                for (int reg = 0; reg < 4; ++reg) {
                    int b = bt * 16 + g * 4 + reg;
                    float hv = tanhf(acc[bt][ct][reg] + bh[ct - 1]);
                    c[(size_t)n * WB + b * 64 + u] = (unsigned short)f2bf(hv);
                }
            }
        }
    }
}

// ---------- preproj via MFMA: [32 b][64 u] @ Wout[64][80 (m*16+u')] per n ----------
__launch_bounds__(256)
__global__ void preproj_mfma(const unsigned short* __restrict__ c,  // [NN][b*64+u] bf16
                             const float* __restrict__ Wout,        // [(u*5+m)*16+u']
                             float* __restrict__ d0,
                             unsigned short* __restrict__ dd1, unsigned short* __restrict__ dd2,
                             unsigned short* __restrict__ dd3, unsigned short* __restrict__ dd4) {
    __shared__ __align__(16) unsigned short sW[80 * 72];    // [col=m*16+u'][k=u] (11.3 KB)
    int t = threadIdx.x;
    for (int i = t; i < 80 * 64; i += 256) {
        int col = i >> 6, k = i & 63;
        int m = col >> 4, up = col & 15;
        sW[col * 72 + k] = (unsigned short)f2bf(Wout[(k * 5 + m) * 16 + up]);
    }
    __syncthreads();
    int lane = t & 63, w = t >> 6;
    int r = lane & 15, g = lane >> 4;
    bf16x8 wf[5][2];
#pragma unroll
    for (int ct = 0; ct < 5; ++ct)
#pragma unroll
        for (int kt = 0; kt < 2; ++kt)
            wf[ct][kt] = *(const bf16x8*)(sW + (ct * 16 + r) * 72 + kt * 32 + g * 8);

    for (int i = 0; i < 2; ++i) {
        int n = blockIdx.x * 8 + w * 2 + i;
        f32x4 acc[2][5];
#pragma unroll
        for (int bt = 0; bt < 2; ++bt)
#pragma unroll
            for (int ct = 0; ct < 5; ++ct)
                acc[bt][ct] = (f32x4){0.f, 0.f, 0.f, 0.f};
#pragma unroll
        for (int kt = 0; kt < 2; ++kt) {
            bf16x8 a[2];
#pragma unroll
            for (int bt = 0; bt < 2; ++bt)
                a[bt] = *(const bf16x8*)(c + (size_t)n * WB + (bt * 16 + r) * 64
                                         + kt * 32 + g * 8);
#pragma unroll
            for (int bt = 0; bt < 2; ++bt)
#pragma unroll
                for (int ct = 0; ct < 5; ++ct)
                    acc[bt][ct] = __builtin_amdgcn_mfma_f32_16x16x32_bf16(
                        a[bt], wf[ct][kt], acc[bt][ct], 0, 0, 0);
        }
#pragma unroll
        for (int bt = 0; bt < 2; ++bt) {
#pragma unroll
            for (int reg = 0; reg < 4; ++reg) {
                int b = bt * 16 + g * 4 + reg;
                d0[(size_t)n * WD + b * 16 + r] = acc[bt][0][reg];
            }
#pragma unroll
            for (int ct = 1; ct < 5; ++ct) {
                unsigned short* dp = (ct == 1) ? dd1 : (ct == 2) ? dd2 : (ct == 3) ? dd3 : dd4;
#pragma unroll
                for (int reg = 0; reg < 4; ++reg) {
                    int b = bt * 16 + g * 4 + reg;
                    dp[(size_t)n * WD + b * 16 + r] = (unsigned short)f2bf(acc[bt][ct][reg]);
                }
            }
        }
    }
}

// ---------- fused B2+final: per row, gather S1@g1 and S2@g3, then combine ----------
// out = -sigmoid(theta+bl) * tanh(d0 - d2 - d4 + S1@g1 + S2@g3 + bl)
__launch_bounds__(64)
__global__ void finalspmm_kernel(const unsigned short* __restrict__ g1, const unsigned short* __restrict__ g3,
                                 const int* __restrict__ rp1, const int* __restrict__ ecol1, const float* __restrict__ eval1,
                                 const int* __restrict__ rp2, const int* __restrict__ ecol2, const float* __restrict__ eval2,
                                 const float* __restrict__ theta, const float* __restrict__ d0,
                                 const unsigned short* __restrict__ dd2, const unsigned short* __restrict__ dd4,
                                 const float* __restrict__ b_lat, float* __restrict__ out) {
    __shared__ int scol[64];
    __shared__ float sval[64];
    int blk = blockIdx.x;
    int row = (blk & 7) * 512 + (blk >> 3);   // XCD-chunked, bijective
    int t = threadIdx.x;                      // 64 threads, 8 elems each
    float h[8];
#pragma unroll
    for (int k = 0; k < 8; ++k) h[k] = 0.f;
#pragma unroll
    for (int s = 0; s < 2; ++s) {
        const int* rp = s ? rp2 : rp1;
        const int* ecol = s ? ecol2 : ecol1;
        const float* eval = s ? eval2 : eval1;
        const unsigned short* gin = s ? g3 : g1;
        int beg = rp[row], end = rp[row + 1];
        for (int i0 = beg; i0 < end; i0 += 64) {
            int nn = end - i0; if (nn > 64) nn = 64;
            __syncthreads();
            if (t < nn) { scol[t] = ecol[i0 + t]; sval[t] = eval[i0 + t]; }
            __syncthreads();
#pragma unroll 4
            for (int j = 0; j < nn; ++j) {
                uint4 xv = ((const uint4*)(gin + (size_t)scol[j] * WD))[t];
                float v = sval[j];
                h[0] += v * bf2f(xv.x & 0xffffu);
                h[1] += v * bf2f(xv.x >> 16);
                h[2] += v * bf2f(xv.y & 0xffffu);
                h[3] += v * bf2f(xv.y >> 16);
                h[4] += v * bf2f(xv.z & 0xffffu);
                h[5] += v * bf2f(xv.z >> 16);
                h[6] += v * bf2f(xv.w & 0xffffu);
                h[7] += v * bf2f(xv.w >> 16);
            }
        }
    }
    // combine: i = t*8 + j ; b = i>>4 = t>>1 ; u = (t&1)*8 + j
    size_t base = (size_t)row * WD + t * 8;
    float4 dA = *(const float4*)(d0 + base);
    float4 dB = *(const float4*)(d0 + base + 4);
    uint4 p2 = *(const uint4*)(dd2 + base);
    uint4 p4 = *(const uint4*)(dd4 + base);
    float4 tA = *(const float4*)(theta + base);
    float4 tB = *(const float4*)(theta + base + 4);
    float4 blA = *(const float4*)(b_lat + (t & 1) * 8);
    float4 blB = *(const float4*)(b_lat + (t & 1) * 8 + 4);
    float tot[8], th[8];
    tot[0] = dA.x - bf2f(p2.x & 0xffffu) - bf2f(p4.x & 0xffffu) + h[0] + blA.x;
    tot[1] = dA.y - bf2f(p2.x >> 16)     - bf2f(p4.x >> 16)     + h[1] + blA.y;
    tot[2] = dA.z - bf2f(p2.y & 0xffffu) - bf2f(p4.y & 0xffffu) + h[2] + blA.z;
    tot[3] = dA.w - bf2f(p2.y >> 16)     - bf2f(p4.y >> 16)     + h[3] + blA.w;
    tot[4] = dB.x - bf2f(p2.z & 0xffffu) - bf2f(p4.z & 0xffffu) + h[4] + blB.x;
    tot[5] = dB.y - bf2f(p2.z >> 16)     - bf2f(p4.z >> 16)     + h[5] + blB.y;
    tot[6] = dB.z - bf2f(p2.w & 0xffffu) - bf2f(p4.w & 0xffffu) + h[6] + blB.z;
    tot[7] = dB.w - bf2f(p2.w >> 16)     - bf2f(p4.w >> 16)     + h[7] + blB.w;
    th[0] = tA.x + blA.x; th[1] = tA.y + blA.y; th[2] = tA.z + blA.z; th[3] = tA.w + blA.w;
    th[4] = tB.x + blB.x; th[5] = tB.y + blB.y; th[6] = tB.z + blB.z; th[7] = tB.w + blB.w;
    float res[8];
#pragma unroll
    for (int j = 0; j < 8; ++j)
        res[j] = -(1.f / (1.f + expf(-th[j]))) * tanhf(tot[j]);
    float* po = out + ((size_t)(t >> 1) * NN + row) * 16 + (t & 1) * 8;
    *(float4*)(po)     = make_float4(res[0], res[1], res[2], res[3]);
    *(float4*)(po + 4) = make_float4(res[4], res[5], res[6], res[7]);
}

extern "C" void kernel_launch(void* const* d_in, const int* in_sizes, int n_in,
                              void* d_out, int out_size, void* d_ws, size_t ws_size,
                              hipStream_t stream) {
    const float* y      = (const float*)d_in[1];
    const float* Wtheta = (const float*)d_in[2];
    const float* b_lat  = (const float*)d_in[3];
    const float* Whid   = (const float*)d_in[4];
    const float* b_hid  = (const float*)d_in[5];
    const float* Wout   = (const float*)d_in[6];
    const int*   r1     = (const int*)d_in[7];
    const int*   c1     = (const int*)d_in[8];
    const float* v1     = (const float*)d_in[9];
    const int*   r2     = (const int*)d_in[10];
    const int*   c2     = (const int*)d_in[11];
    const float* v2     = (const float*)d_in[12];
    float* out = (float*)d_out;

    // ---- workspace layout ----
    char* ws = (char*)d_ws;
    size_t off = 0;
    auto alloc = [&](size_t bytes) -> char* {
        char* p = ws + off;
        off += (bytes + 255) & ~(size_t)255;
        return p;
    };
    int*   rp1   = (int*)alloc(4097 * 4);
    int*   rp2   = (int*)alloc(4097 * 4);
    int*   cur1  = (int*)alloc(4096 * 4);            // cur1+cur2 contiguous (single memset)
    int*   cur2  = (int*)alloc(4096 * 4);
    int*   ecol1 = (int*)alloc(NNZE * 4);
    float* eval1 = (float*)alloc(NNZE * 4);
    int*   ecol2 = (int*)alloc(NNZE * 4);
    float* eval2 = (float*)alloc(NNZE * 4);
    unsigned short* xh = (unsigned short*)alloc((size_t)5 * NN * WA * 2); // 20 MB bf16 [m][n][512]
    float* theta = (float*)alloc((size_t)NN * 512 * 4);                   //  8 MB
    char*  creg  = alloc((size_t)NN * WB * 2);                            // 16 MB (c bf16)
    float* d0 = (float*)alloc((size_t)NN * WD * 4);                       //  8 MB
    unsigned short* g1 = (unsigned short*)alloc((size_t)NN * WD * 2);     //  4 MB
    unsigned short* g3 = (unsigned short*)alloc((size_t)NN * WD * 2);     //  4 MB
    if (off > ws_size) return;   // fail loudly if ws too small

    unsigned short* x0h = xh;
    unsigned short* x1h = xh + (size_t)1 * NN * WA;
    unsigned short* x2h = xh + (size_t)2 * NN * WA;
    unsigned short* x3h = xh + (size_t)3 * NN * WA;
    unsigned short* x4h = xh + (size_t)4 * NN * WA;
    unsigned short* cbuf = (unsigned short*)creg;
    // xh dead after projA -> overlay dd1..dd4 (16 MB of 20)
    unsigned short* dd1 = (unsigned short*)((char*)xh + ((size_t)0  << 20));
    unsigned short* dd2 = (unsigned short*)((char*)xh + ((size_t)4  << 20));
    unsigned short* dd3 = (unsigned short*)((char*)xh + ((size_t)8  << 20));
    unsigned short* dd4 = (unsigned short*)((char*)xh + ((size_t)12 << 20));

    // ---- CSR build ----
    hipMemsetAsync(cur1, 0, 2 * 4096 * 4, stream);
    hist2_kernel<<<2 * NNZE / 256, 256, 0, stream>>>(r1, r2, cur1, cur2);
    scan2_kernel<<<2, 256, 0, stream>>>(cur1, rp1, cur2, rp2);
    scatter2_kernel<<<2 * NNZE / 256, 256, 0, stream>>>(r1, c1, v1, r2, c2, v2,
                                                        cur1, cur2, ecol1, eval1, ecol2, eval2);

    // ---- pass A: transpose (bf16, [b*16+f]), 2 narrow spmm launches, MFMA projection ----
    transA_kernel<<<NN, 128, 0, stream>>>(y, x0h);
    {   // x1 = S1@x0, x3 = S2@x0
        SpmmDesc a0 = { x0h, nullptr, nullptr, x1h, rp1, ecol1, eval1, 1.f, 0.f };
        SpmmDesc a1 = { x0h, nullptr, nullptr, x3h, rp2, ecol2, eval2, 1.f, 0.f };
        spmmD_kernel<<<2 * NN, 64, 0, stream>>>(a0, a1, a0, a1, 2);
    }
    {   // x2 = 2*S1@x1 - x0, x4 = 2*S2@x3 - x0
        SpmmDesc a0 = { x1h, x0h, nullptr, x2h, rp1, ecol1, eval1, 2.f, -1.f };
        SpmmDesc a1 = { x3h, x0h, nullptr, x4h, rp2, ecol2, eval2, 2.f, -1.f };
        spmmD_kernel<<<2 * NN, 64, 0, stream>>>(a0, a1, a0, a1, 2);
    }
    projA_mfma<<<NN / 8, 256, 0, stream>>>(xh, Wtheta, Whid, b_hid, theta, cbuf);

    // ---- pass B (commuted + telescoped): preproj, then TWO spmm rounds total ----
    preproj_mfma<<<NN / 8, 256, 0, stream>>>(cbuf, Wout, d0, dd1, dd2, dd3, dd4);
    {   // g1 = 2*S1@d2 + d1 (bf16), g3 = 2*S2@d4 + d3 (bf16)
        SpmmDesc a0 = { dd2, dd1, nullptr, g1, rp1, ecol1, eval1, 2.f, 1.f };
        SpmmDesc a1 = { dd4, dd3, nullptr, g3, rp2, ecol2, eval2, 2.f, 1.f };
        spmmD_kernel<<<2 * NN, 64, 0, stream>>>(a0, a1, a0, a1, 2);
    }
    // fused: out = -sigmoid(theta+bl)*tanh(d0 - d2 - d4 + S1@g1 + S2@g3 + bl)
    finalspmm_kernel<<<NN, 64, 0, stream>>>(g1, g3, rp1, ecol1, eval1, rp2, ecol2, eval2,
                                            theta, d0, dd2, dd4, b_lat, out);
}